// Round 2
// baseline (7600.735 us; speedup 1.0000x reference)
//
#include <hip/hip_runtime.h>
#include <hip/hip_bf16.h>
#include <math.h>

using bf16 = __hip_bfloat16;

// ---------------------------------------------------------------------------
// Generic tiled fp32 GEMM: C[N,M] = A[N,K] @ W[M,K]^T + bias
// Tile: 128 rows x 128 cols, BK=16, 256 threads, 8x8 micro-tile.
// Flags: CLEAN (-inf->0 on A), RELU, BF16O (bf16 output), SPLIT (A is concat
// of A[:, :KA1] and A2[:, KA1:K]), ADDX (C += eps * X, X row-major N x M).
// ---------------------------------------------------------------------------
template <bool CLEAN, bool RELU, bool BF16O, bool SPLIT, bool ADDX>
__global__ __launch_bounds__(256) void gemm_k(
    const float* __restrict__ A, const float* __restrict__ A2, int KA1,
    const float* __restrict__ W, const float* __restrict__ bias,
    float* __restrict__ Cf, bf16* __restrict__ Cb,
    const float* __restrict__ X, const float* __restrict__ epsp,
    int N, int M, int K) {
  constexpr int BK = 16;
  constexpr int LDP = 132;  // 128 + 4 pad: keeps 16B alignment, breaks conflicts
  __shared__ float At[BK * LDP];
  __shared__ float Wt[BK * LDP];

  const int tid = threadIdx.x;
  const int tx = tid & 15;   // output-col group
  const int ty = tid >> 4;   // node-row group
  const int row0 = blockIdx.y * 128;
  const int m0 = blockIdx.x * 128;

  float acc[8][8] = {};

  for (int kc = 0; kc < K; kc += BK) {
    // ---- stage A tile (128 rows x 16 k), transposed into At[k][row] ----
#pragma unroll
    for (int i = 0; i < 2; i++) {
      int idx = tid + i * 256;        // 0..511 (512 float4 per tile)
      int r = idx >> 2;               // 0..127
      int k4 = idx & 3;               // 0..3
      int kg = kc + k4 * 4;
      float4 v = make_float4(0.f, 0.f, 0.f, 0.f);
      int row = row0 + r;
      if (row < N) {
        if (!SPLIT || kg < KA1) {
          int lda = SPLIT ? KA1 : K;
          v = *(const float4*)(A + (size_t)row * lda + kg);
        } else {
          v = *(const float4*)(A2 + (size_t)row * (K - KA1) + (kg - KA1));
        }
      }
      if (CLEAN) {
        v.x = (v.x < -1e30f) ? 0.f : v.x;
        v.y = (v.y < -1e30f) ? 0.f : v.y;
        v.z = (v.z < -1e30f) ? 0.f : v.z;
        v.w = (v.w < -1e30f) ? 0.f : v.w;
      }
      At[(k4 * 4 + 0) * LDP + r] = v.x;
      At[(k4 * 4 + 1) * LDP + r] = v.y;
      At[(k4 * 4 + 2) * LDP + r] = v.z;
      At[(k4 * 4 + 3) * LDP + r] = v.w;
    }
    // ---- stage W tile (128 outs x 16 k), transposed into Wt[k][m] ----
#pragma unroll
    for (int i = 0; i < 2; i++) {
      int idx = tid + i * 256;
      int r = idx >> 2;
      int k4 = idx & 3;
      int kg = kc + k4 * 4;
      float4 v = *(const float4*)(W + (size_t)(m0 + r) * K + kg);
      Wt[(k4 * 4 + 0) * LDP + r] = v.x;
      Wt[(k4 * 4 + 1) * LDP + r] = v.y;
      Wt[(k4 * 4 + 2) * LDP + r] = v.z;
      Wt[(k4 * 4 + 3) * LDP + r] = v.w;
    }
    __syncthreads();
#pragma unroll
    for (int k = 0; k < BK; k++) {
      const float4 a0 = *(const float4*)&At[k * LDP + ty * 8];
      const float4 a1 = *(const float4*)&At[k * LDP + ty * 8 + 4];
      const float4 w0 = *(const float4*)&Wt[k * LDP + tx * 8];
      const float4 w1 = *(const float4*)&Wt[k * LDP + tx * 8 + 4];
      const float av[8] = {a0.x, a0.y, a0.z, a0.w, a1.x, a1.y, a1.z, a1.w};
      const float wv[8] = {w0.x, w0.y, w0.z, w0.w, w1.x, w1.y, w1.z, w1.w};
#pragma unroll
      for (int i = 0; i < 8; i++)
#pragma unroll
        for (int j = 0; j < 8; j++) acc[i][j] += av[i] * wv[j];
    }
    __syncthreads();
  }

  const float ep = ADDX ? epsp[0] : 0.f;
#pragma unroll
  for (int i = 0; i < 8; i++) {
    int row = row0 + ty * 8 + i;
    if (row >= N) continue;
#pragma unroll
    for (int j = 0; j < 8; j++) {
      int col = m0 + tx * 8 + j;
      float v = acc[i][j] + bias[col];
      if (ADDX) v += ep * X[(size_t)row * M + col];
      if (RELU) v = fmaxf(v, 0.f);
      if (BF16O)
        Cb[(size_t)row * M + col] = __float2bfloat16(v);
      else
        Cf[(size_t)row * M + col] = v;
    }
  }
}

// ---------------------------------------------------------------------------
// init: agg_sum = 0, agg_max = -inf, stats[0:256] = 0
// ---------------------------------------------------------------------------
__global__ void init_k(float* __restrict__ aggs, float* __restrict__ aggm,
                       float* __restrict__ stats, int nd4) {
  const float4 z = make_float4(0.f, 0.f, 0.f, 0.f);
  const float ninf = -INFINITY;
  const float4 mi = make_float4(ninf, ninf, ninf, ninf);
  for (int g = blockIdx.x * 256 + threadIdx.x; g < nd4;
       g += gridDim.x * 256) {
    ((float4*)aggs)[g] = z;
    ((float4*)aggm)[g] = mi;
  }
  if (blockIdx.x == 0 && threadIdx.x < 256) stats[threadIdx.x] = 0.f;
}

// ---------------------------------------------------------------------------
// scatter: for each edge e: agg_sum[dst] += x[src]; agg_max[dst] max= xi[src]
// 32 threads per edge, each thread does a float4 chunk (4 scalar atomics).
// ---------------------------------------------------------------------------
__device__ inline void atomicMaxF(float* addr, float v) {
  int iv = __float_as_int(v);
  if (iv >= 0) {
    atomicMax((int*)addr, iv);
  } else {
    atomicMin((unsigned int*)addr, __float_as_uint(v));
  }
}

__global__ __launch_bounds__(256) void scatter_k(
    const int* __restrict__ edges, const float* __restrict__ x,
    const float* __restrict__ xi, float* __restrict__ aggs,
    float* __restrict__ aggm, int E) {
  long long gid = (long long)blockIdx.x * 256 + threadIdx.x;
  int e = (int)(gid >> 5);
  if (e >= E) return;
  int f = (int)(gid & 31) * 4;
  int src = edges[e];
  int dst = edges[(size_t)E + e];
  const float4 xs = *(const float4*)(x + (size_t)src * 128 + f);
  const float4 xv = *(const float4*)(xi + (size_t)src * 128 + f);
  float* ps = aggs + (size_t)dst * 128 + f;
  float* pm = aggm + (size_t)dst * 128 + f;
  atomicAdd(ps + 0, xs.x);
  atomicAdd(ps + 1, xs.y);
  atomicAdd(ps + 2, xs.z);
  atomicAdd(ps + 3, xs.w);
  atomicMaxF(pm + 0, xv.x);
  atomicMaxF(pm + 1, xv.y);
  atomicMaxF(pm + 2, xv.z);
  atomicMaxF(pm + 3, xv.w);
}

// ---------------------------------------------------------------------------
// GRU elementwise: rnn = (1-z)*tanh(inn + r*hn) + z*x
// gi/gh are chunk-local (row 0 == global row r0); x/rnn passed pre-offset.
// ---------------------------------------------------------------------------
__global__ __launch_bounds__(256) void gru_k(const bf16* __restrict__ gi,
                                             const bf16* __restrict__ gh,
                                             const float* __restrict__ x,
                                             float* __restrict__ rnn,
                                             int total) {
  int g = blockIdx.x * 256 + threadIdx.x;
  if (g >= total) return;
  int n = g >> 7;
  int d = g & 127;
  size_t b = (size_t)n * 384 + d;
  float ir = __bfloat162float(gi[b]);
  float iz = __bfloat162float(gi[b + 128]);
  float in = __bfloat162float(gi[b + 256]);
  float hr = __bfloat162float(gh[b]);
  float hz = __bfloat162float(gh[b + 128]);
  float hn = __bfloat162float(gh[b + 256]);
  float r = 1.f / (1.f + __expf(-(ir + hr)));
  float z = 1.f / (1.f + __expf(-(iz + hz)));
  float nc = tanhf(in + r * hn);
  float xv = x[g];
  rnn[g] = (1.f - z) * nc + z * xv;
}

// ---------------------------------------------------------------------------
// BatchNorm: stats (sum, sumsq per channel), finalize, apply (in-place)
// ---------------------------------------------------------------------------
__global__ __launch_bounds__(256) void bn_stats_k(const float* __restrict__ h,
                                                  float* __restrict__ stats,
                                                  int total) {
  float s = 0.f, q = 0.f;
  for (int g = blockIdx.x * 256 + threadIdx.x; g < total;
       g += gridDim.x * 256) {
    float v = h[g];
    s += v;
    q += v * v;
  }
  __shared__ float ls[256], lq[256];
  int tid = threadIdx.x;
  ls[tid] = s;
  lq[tid] = q;
  __syncthreads();
  if (tid < 128) {
    atomicAdd(&stats[tid], ls[tid] + ls[tid + 128]);
    atomicAdd(&stats[128 + tid], lq[tid] + lq[tid + 128]);
  }
}

__global__ void bn_final_k(float* __restrict__ stats,
                           const float* __restrict__ gamma,
                           const float* __restrict__ beta, int N) {
  int d = threadIdx.x;
  if (d >= 128) return;
  float invn = 1.f / (float)N;
  float mean = stats[d] * invn;
  float var = stats[128 + d] * invn - mean * mean;
  var = fmaxf(var, 0.f);
  float sc = gamma[d] * rsqrtf(var + 1e-5f);
  stats[256 + d] = sc;
  stats[384 + d] = beta[d] - mean * sc;
}

__global__ __launch_bounds__(256) void bn_apply_k(float* __restrict__ out,
                                                  const float* __restrict__ sc,
                                                  const float* __restrict__ sh,
                                                  int nd4) {
  int g = blockIdx.x * 256 + threadIdx.x;
  if (g >= nd4) return;
  float4 v = ((float4*)out)[g];
  int d = (g & 31) * 4;
  v.x = v.x * sc[d + 0] + sh[d + 0];
  v.y = v.y * sc[d + 1] + sh[d + 1];
  v.z = v.z * sc[d + 2] + sh[d + 2];
  v.w = v.w * sc[d + 3] + sh[d + 3];
  ((float4*)out)[g] = v;
}

// ---------------------------------------------------------------------------
extern "C" void kernel_launch(void* const* d_in, const int* in_sizes, int n_in,
                              void* d_out, int out_size, void* d_ws,
                              size_t ws_size, hipStream_t stream) {
  (void)n_in;
  (void)out_size;
  const float* x = (const float*)d_in[0];
  const int* edges = (const int*)d_in[1];
  const float* W_aff = (const float*)d_in[2];
  const float* b_aff = (const float*)d_in[3];
  const float* W_ih = (const float*)d_in[4];
  const float* b_ih = (const float*)d_in[5];
  const float* W_hh = (const float*)d_in[6];
  const float* b_hh = (const float*)d_in[7];
  const float* W_merge = (const float*)d_in[8];
  const float* b_merge = (const float*)d_in[9];
  const float* epsp = (const float*)d_in[10];
  const float* W1 = (const float*)d_in[11];
  const float* b1 = (const float*)d_in[12];
  const float* W2 = (const float*)d_in[13];
  const float* b2 = (const float*)d_in[14];
  const float* gamma = (const float*)d_in[15];
  const float* beta = (const float*)d_in[16];

  const int N = in_sizes[0] / 128;
  const int E = in_sizes[1] / 2;
  const size_t nd = (size_t)N * 128;

  // ---- workspace plan (byte offsets), hard floor N*1536 + gi/gh chunk ----
  //  [0,        N*512)  aggm  -> rnn (in place) -> low half of hid
  //  [N*512,    N*1024) aggs  -> high half of hid
  //  [N*1024,   N*1536) xi    -> hpre
  //  [N*1536,   +2*Nc*768)   gi (bf16 Nc*384) | gh (bf16 Nc*384), Nc=chunk rows
  //  [..,       +2048)       stats[512]
  // gi/gh are chunked over node ranges (GRU is row-local) so peak ws adapts
  // to ws_size: C=1 -> 307 MB ... C=50 -> 157 MB.
  int C = 50;
  const int cand[] = {1, 2, 4, 5, 8, 10, 20, 25, 50};
  for (int ci = 0; ci < 9; ci++) {
    int c = cand[ci];
    int nc = (N + c - 1) / c;
    size_t need = (size_t)N * 1536 + (size_t)2 * nc * 768 + 2048;
    if (need <= ws_size) {
      C = c;
      break;
    }
  }
  const int Nc = (N + C - 1) / C;

  char* base = (char*)d_ws;
  float* aggm = (float*)base;
  float* rnn = aggm;
  float* aggs = (float*)(base + (size_t)N * 512);
  float* xi = (float*)(base + (size_t)N * 1024);
  float* hpre = xi;
  bf16* gi = (bf16*)(base + (size_t)N * 1536);
  bf16* gh = gi + (size_t)Nc * 384;
  float* hid = (float*)base;  // spans aggm+aggs regions (dead by then)
  float* stats = (float*)(base + (size_t)N * 1536 + (size_t)2 * Nc * 768);
  float* out = (float*)d_out;

  const int ny = (N + 127) / 128;
  dim3 blk(256);

  // K1: xi = x @ W_aff^T + b_aff
  gemm_k<false, false, false, false, false><<<dim3(1, ny), blk, 0, stream>>>(
      x, nullptr, 0, W_aff, b_aff, xi, nullptr, nullptr, nullptr, N, 128, 128);
  // K2: init agg buffers + stats
  init_k<<<2048, blk, 0, stream>>>(aggs, aggm, stats, (int)(nd / 4));
  // K3: scatter add/max over edges
  scatter_k<<<(int)(((long long)E * 32 + 255) / 256), blk, 0, stream>>>(
      edges, x, xi, aggs, aggm, E);
  // K4/K5/K6 per node-chunk: gi, gh (bf16), GRU -> rnn (in place over aggm)
  for (int c = 0; c < C; c++) {
    int r0 = c * Nc;
    if (r0 >= N) break;
    int Nr = (N - r0 < Nc) ? (N - r0) : Nc;
    int nyc = (Nr + 127) / 128;
    gemm_k<true, false, true, false, false><<<dim3(3, nyc), blk, 0, stream>>>(
        aggm + (size_t)r0 * 128, nullptr, 0, W_ih, b_ih, nullptr, gi, nullptr,
        nullptr, Nr, 384, 128);
    gemm_k<false, false, true, false, false><<<dim3(3, nyc), blk, 0, stream>>>(
        x + (size_t)r0 * 128, nullptr, 0, W_hh, b_hh, nullptr, gh, nullptr,
        nullptr, Nr, 384, 128);
    gru_k<<<(Nr * 128 + 255) / 256, blk, 0, stream>>>(
        gi, gh, x + (size_t)r0 * 128, rnn + (size_t)r0 * 128, Nr * 128);
  }
  // K7: hpre = concat(aggs, rnn) @ W_merge^T + b_merge + eps*x  (into xi region)
  gemm_k<false, false, false, true, true><<<dim3(1, ny), blk, 0, stream>>>(
      aggs, rnn, 128, W_merge, b_merge, hpre, nullptr, x, epsp, N, 128, 256);
  // K8: hid = relu(hpre @ W1^T + b1)   (hid spans dead rnn+aggs regions)
  gemm_k<false, true, false, false, false><<<dim3(2, ny), blk, 0, stream>>>(
      hpre, nullptr, 0, W1, b1, hid, nullptr, nullptr, nullptr, N, 256, 128);
  // K9: out = relu(hid @ W2^T + b2)
  gemm_k<false, true, false, false, false><<<dim3(1, ny), blk, 0, stream>>>(
      hid, nullptr, 0, W2, b2, out, nullptr, nullptr, nullptr, N, 128, 256);
  // K10-12: batchnorm
  bn_stats_k<<<512, blk, 0, stream>>>(out, stats, (int)nd);
  bn_final_k<<<1, 128, 0, stream>>>(stats, gamma, beta, N);
  bn_apply_k<<<(int)((nd / 4 + 255) / 256), blk, 0, stream>>>(
      out, stats + 256, stats + 384, (int)(nd / 4));
}

// Round 3
// 1279.657 us; speedup vs baseline: 5.9397x; 5.9397x over previous
//
#include <hip/hip_runtime.h>
#include <hip/hip_bf16.h>
#include <math.h>

using bf16 = __hip_bfloat16;

// ---------------------------------------------------------------------------
// Generic tiled fp32 GEMM: C[N,M] = A[N,K] @ W[M,K]^T + bias
// Tile: 128 rows x 128 cols, BK=16, 256 threads, 8x8 micro-tile.
// Flags: RELU, BF16O (bf16 output), SPLIT (A is concat of A[:, :KA1] and
// A2[:, KA1:K]), ADDX (C += eps * X, X row-major N x M).
// ---------------------------------------------------------------------------
template <bool RELU, bool BF16O, bool SPLIT, bool ADDX>
__global__ __launch_bounds__(256) void gemm_k(
    const float* __restrict__ A, const float* __restrict__ A2, int KA1,
    const float* __restrict__ W, const float* __restrict__ bias,
    float* __restrict__ Cf, bf16* __restrict__ Cb,
    const float* __restrict__ X, const float* __restrict__ epsp,
    int N, int M, int K) {
  constexpr int BK = 16;
  constexpr int LDP = 132;  // 128 + 4 pad: keeps 16B alignment, breaks conflicts
  __shared__ float At[BK * LDP];
  __shared__ float Wt[BK * LDP];

  const int tid = threadIdx.x;
  const int tx = tid & 15;   // output-col group
  const int ty = tid >> 4;   // node-row group
  const int row0 = blockIdx.y * 128;
  const int m0 = blockIdx.x * 128;

  float acc[8][8] = {};

  for (int kc = 0; kc < K; kc += BK) {
    // ---- stage A tile (128 rows x 16 k), transposed into At[k][row] ----
#pragma unroll
    for (int i = 0; i < 2; i++) {
      int idx = tid + i * 256;        // 0..511 (512 float4 per tile)
      int r = idx >> 2;               // 0..127
      int k4 = idx & 3;               // 0..3
      int kg = kc + k4 * 4;
      float4 v = make_float4(0.f, 0.f, 0.f, 0.f);
      int row = row0 + r;
      if (row < N) {
        if (!SPLIT || kg < KA1) {
          int lda = SPLIT ? KA1 : K;
          v = *(const float4*)(A + (size_t)row * lda + kg);
        } else {
          v = *(const float4*)(A2 + (size_t)row * (K - KA1) + (kg - KA1));
        }
      }
      At[(k4 * 4 + 0) * LDP + r] = v.x;
      At[(k4 * 4 + 1) * LDP + r] = v.y;
      At[(k4 * 4 + 2) * LDP + r] = v.z;
      At[(k4 * 4 + 3) * LDP + r] = v.w;
    }
    // ---- stage W tile (128 outs x 16 k), transposed into Wt[k][m] ----
#pragma unroll
    for (int i = 0; i < 2; i++) {
      int idx = tid + i * 256;
      int r = idx >> 2;
      int k4 = idx & 3;
      int kg = kc + k4 * 4;
      float4 v = *(const float4*)(W + (size_t)(m0 + r) * K + kg);
      Wt[(k4 * 4 + 0) * LDP + r] = v.x;
      Wt[(k4 * 4 + 1) * LDP + r] = v.y;
      Wt[(k4 * 4 + 2) * LDP + r] = v.z;
      Wt[(k4 * 4 + 3) * LDP + r] = v.w;
    }
    __syncthreads();
#pragma unroll
    for (int k = 0; k < BK; k++) {
      const float4 a0 = *(const float4*)&At[k * LDP + ty * 8];
      const float4 a1 = *(const float4*)&At[k * LDP + ty * 8 + 4];
      const float4 w0 = *(const float4*)&Wt[k * LDP + tx * 8];
      const float4 w1 = *(const float4*)&Wt[k * LDP + tx * 8 + 4];
      const float av[8] = {a0.x, a0.y, a0.z, a0.w, a1.x, a1.y, a1.z, a1.w};
      const float wv[8] = {w0.x, w0.y, w0.z, w0.w, w1.x, w1.y, w1.z, w1.w};
#pragma unroll
      for (int i = 0; i < 8; i++)
#pragma unroll
        for (int j = 0; j < 8; j++) acc[i][j] += av[i] * wv[j];
    }
    __syncthreads();
  }

  const float ep = ADDX ? epsp[0] : 0.f;
#pragma unroll
  for (int i = 0; i < 8; i++) {
    int row = row0 + ty * 8 + i;
    if (row >= N) continue;
#pragma unroll
    for (int j = 0; j < 8; j++) {
      int col = m0 + tx * 8 + j;
      float v = acc[i][j] + bias[col];
      if (ADDX) v += ep * X[(size_t)row * M + col];
      if (RELU) v = fmaxf(v, 0.f);
      if (BF16O)
        Cb[(size_t)row * M + col] = __float2bfloat16(v);
      else
        Cf[(size_t)row * M + col] = v;
    }
  }
}

// ---------------------------------------------------------------------------
// CSR build: zero deg+stats; histogram by dst; block scan; fill buckets.
// ---------------------------------------------------------------------------
__global__ __launch_bounds__(256) void init0_k(int* __restrict__ deg,
                                               float* __restrict__ stats,
                                               int N) {
  int i = blockIdx.x * 256 + threadIdx.x;
  if (i < N) deg[i] = 0;
  if (blockIdx.x == 0) stats[threadIdx.x] = 0.f;        // zeros stats[0:256]
  if (blockIdx.x == 1) stats[256 + threadIdx.x] = 0.f;  // scale/shift region
}

__global__ __launch_bounds__(256) void hist_k(const int* __restrict__ edges,
                                              int* __restrict__ deg, int E) {
  int e = blockIdx.x * 256 + threadIdx.x;
  if (e < E) atomicAdd(&deg[edges[(size_t)E + e]], 1);
}

__global__ __launch_bounds__(256) void scan1_k(const int* __restrict__ deg,
                                               int* __restrict__ off,
                                               int* __restrict__ bsums, int N) {
  __shared__ int s[256];
  int t = threadIdx.x;
  int i = blockIdx.x * 256 + t;
  int v = (i < N) ? deg[i] : 0;
  s[t] = v;
  __syncthreads();
#pragma unroll
  for (int d = 1; d < 256; d <<= 1) {
    int u = (t >= d) ? s[t - d] : 0;
    __syncthreads();
    s[t] += u;
    __syncthreads();
  }
  if (i < N) off[i] = s[t] - v;  // exclusive within block
  if (t == 255) bsums[blockIdx.x] = s[255];
}

__global__ __launch_bounds__(512) void scan2_k(int* __restrict__ bsums,
                                               int nb) {
  __shared__ int s[512];
  int t = threadIdx.x;
  int v = (t < nb) ? bsums[t] : 0;
  s[t] = v;
  __syncthreads();
#pragma unroll
  for (int d = 1; d < 512; d <<= 1) {
    int u = (t >= d) ? s[t - d] : 0;
    __syncthreads();
    s[t] += u;
    __syncthreads();
  }
  if (t < nb) bsums[t] = s[t] - v;  // exclusive block offsets
}

__global__ __launch_bounds__(256) void scan3_k(int* __restrict__ off,
                                               int* __restrict__ cur,
                                               const int* __restrict__ bsums,
                                               int N, int E) {
  int i = blockIdx.x * 256 + threadIdx.x;
  if (i < N) {
    int o = off[i] + bsums[blockIdx.x];
    off[i] = o;
    cur[i] = o;
  }
  if (i == 0) off[N] = E;
}

__global__ __launch_bounds__(256) void fill_k(const int* __restrict__ edges,
                                              int* __restrict__ cur,
                                              int* __restrict__ bucket, int E) {
  int e = blockIdx.x * 256 + threadIdx.x;
  if (e >= E) return;
  int src = edges[e];
  int dst = edges[(size_t)E + e];
  int pos = atomicAdd(&cur[dst], 1);
  bucket[pos] = src;
}

// ---------------------------------------------------------------------------
// gather-reduce: 128 threads per node (one per feature), 2 nodes per block.
// Registers only — no atomics. aggm gets 0 for empty segments (CLEAN fused).
// ---------------------------------------------------------------------------
__global__ __launch_bounds__(256) void gather_k(
    const int* __restrict__ off, const int* __restrict__ bucket,
    const float* __restrict__ x, const float* __restrict__ xi,
    float* __restrict__ aggs, float* __restrict__ aggm, int N) {
  int node = blockIdx.x * 2 + (threadIdx.x >> 7);
  int f = threadIdx.x & 127;
  if (node >= N) return;
  int j0 = off[node], jend = off[node + 1];
  float s = 0.f, m = -INFINITY;
  int j = j0;
  int src_next = (j < jend) ? bucket[j] : 0;
  while (j < jend) {
    int src = src_next;
    j++;
    if (j < jend) src_next = bucket[j];  // prefetch next index
    size_t b = (size_t)src * 128 + f;
    s += x[b];
    m = fmaxf(m, xi[b]);
  }
  size_t o = (size_t)node * 128 + f;
  aggs[o] = s;
  aggm[o] = (jend > j0) ? m : 0.f;
}

// ---------------------------------------------------------------------------
// GRU elementwise: rnn = (1-z)*tanh(inn + r*hn) + z*x
// ---------------------------------------------------------------------------
__global__ __launch_bounds__(256) void gru_k(const bf16* __restrict__ gi,
                                             const bf16* __restrict__ gh,
                                             const float* __restrict__ x,
                                             float* __restrict__ rnn,
                                             int total) {
  int g = blockIdx.x * 256 + threadIdx.x;
  if (g >= total) return;
  int n = g >> 7;
  int d = g & 127;
  size_t b = (size_t)n * 384 + d;
  float ir = __bfloat162float(gi[b]);
  float iz = __bfloat162float(gi[b + 128]);
  float in = __bfloat162float(gi[b + 256]);
  float hr = __bfloat162float(gh[b]);
  float hz = __bfloat162float(gh[b + 128]);
  float hn = __bfloat162float(gh[b + 256]);
  float r = 1.f / (1.f + __expf(-(ir + hr)));
  float z = 1.f / (1.f + __expf(-(iz + hz)));
  float nc = tanhf(in + r * hn);
  float xv = x[g];
  rnn[g] = (1.f - z) * nc + z * xv;
}

// ---------------------------------------------------------------------------
// BatchNorm: stats (sum, sumsq per channel), finalize, apply (in-place)
// ---------------------------------------------------------------------------
__global__ __launch_bounds__(256) void bn_stats_k(const float* __restrict__ h,
                                                  float* __restrict__ stats,
                                                  int total) {
  float s = 0.f, q = 0.f;
  for (int g = blockIdx.x * 256 + threadIdx.x; g < total;
       g += gridDim.x * 256) {
    float v = h[g];
    s += v;
    q += v * v;
  }
  __shared__ float ls[256], lq[256];
  int tid = threadIdx.x;
  ls[tid] = s;
  lq[tid] = q;
  __syncthreads();
  if (tid < 128) {
    atomicAdd(&stats[tid], ls[tid] + ls[tid + 128]);
    atomicAdd(&stats[128 + tid], lq[tid] + lq[tid + 128]);
  }
}

__global__ void bn_final_k(float* __restrict__ stats,
                           const float* __restrict__ gamma,
                           const float* __restrict__ beta, int N) {
  int d = threadIdx.x;
  if (d >= 128) return;
  float invn = 1.f / (float)N;
  float mean = stats[d] * invn;
  float var = stats[128 + d] * invn - mean * mean;
  var = fmaxf(var, 0.f);
  float sc = gamma[d] * rsqrtf(var + 1e-5f);
  stats[256 + d] = sc;
  stats[384 + d] = beta[d] - mean * sc;
}

__global__ __launch_bounds__(256) void bn_apply_k(float* __restrict__ out,
                                                  const float* __restrict__ sc,
                                                  const float* __restrict__ sh,
                                                  int nd4) {
  int g = blockIdx.x * 256 + threadIdx.x;
  if (g >= nd4) return;
  float4 v = ((float4*)out)[g];
  int d = (g & 31) * 4;
  v.x = v.x * sc[d + 0] + sh[d + 0];
  v.y = v.y * sc[d + 1] + sh[d + 1];
  v.z = v.z * sc[d + 2] + sh[d + 2];
  v.w = v.w * sc[d + 3] + sh[d + 3];
  ((float4*)out)[g] = v;
}

// ---------------------------------------------------------------------------
extern "C" void kernel_launch(void* const* d_in, const int* in_sizes, int n_in,
                              void* d_out, int out_size, void* d_ws,
                              size_t ws_size, hipStream_t stream) {
  (void)n_in;
  (void)out_size;
  const float* x = (const float*)d_in[0];
  const int* edges = (const int*)d_in[1];
  const float* W_aff = (const float*)d_in[2];
  const float* b_aff = (const float*)d_in[3];
  const float* W_ih = (const float*)d_in[4];
  const float* b_ih = (const float*)d_in[5];
  const float* W_hh = (const float*)d_in[6];
  const float* b_hh = (const float*)d_in[7];
  const float* W_merge = (const float*)d_in[8];
  const float* b_merge = (const float*)d_in[9];
  const float* epsp = (const float*)d_in[10];
  const float* W1 = (const float*)d_in[11];
  const float* b1 = (const float*)d_in[12];
  const float* W2 = (const float*)d_in[13];
  const float* b2 = (const float*)d_in[14];
  const float* gamma = (const float*)d_in[15];
  const float* beta = (const float*)d_in[16];

  const int N = in_sizes[0] / 128;
  const int E = in_sizes[1] / 2;
  const size_t nd = (size_t)N * 128;

  // ---- workspace plan ----
  //  [0,        N*512)  aggm -> rnn (in place) -> low half of hid
  //  [N*512,    N*1024) aggs -> high half of hid
  //  [N*1024,   N*1536) xi   -> hpre
  //  [N*1536,   +2*Nc*768)  gi | gh  (bf16, chunked over node ranges)
  //  [..,       +2048)      stats[512]
  //  [..,       +CSR)       deg[N], off[N+1], cur[N], bucket[E], bsums[512]
  const size_t csr_bytes = ((size_t)3 * N + 1 + E + 512) * 4;
  int C = 50;
  const int cand[] = {1, 2, 4, 5, 8, 10, 20, 25, 50};
  for (int ci = 0; ci < 9; ci++) {
    int c = cand[ci];
    int nc = (N + c - 1) / c;
    size_t need = (size_t)N * 1536 + (size_t)2 * nc * 768 + 2048 + csr_bytes;
    if (need <= ws_size) {
      C = c;
      break;
    }
  }
  const int Nc = (N + C - 1) / C;

  char* base = (char*)d_ws;
  float* aggm = (float*)base;
  float* rnn = aggm;
  float* aggs = (float*)(base + (size_t)N * 512);
  float* xi = (float*)(base + (size_t)N * 1024);
  float* hpre = xi;
  bf16* gi = (bf16*)(base + (size_t)N * 1536);
  bf16* gh = gi + (size_t)Nc * 384;
  float* hid = (float*)base;  // spans aggm+aggs regions (dead by then)
  float* stats = (float*)(base + (size_t)N * 1536 + (size_t)2 * Nc * 768);
  int* deg = (int*)(stats + 512);
  int* off = deg + N;
  int* cur = off + N + 1;
  int* bucket = cur + N;
  int* bsums = bucket + E;
  float* out = (float*)d_out;

  const int ny = (N + 127) / 128;
  const int nblk = (N + 255) / 256;  // scan granularity (<=512 blocks)
  const int eblk = (E + 255) / 256;
  dim3 blk(256);

  // ---- CSR build (no float atomics anywhere) ----
  init0_k<<<nblk, blk, 0, stream>>>(deg, stats, N);
  hist_k<<<eblk, blk, 0, stream>>>(edges, deg, E);
  scan1_k<<<nblk, blk, 0, stream>>>(deg, off, bsums, N);
  scan2_k<<<1, 512, 0, stream>>>(bsums, nblk);
  scan3_k<<<nblk, blk, 0, stream>>>(off, cur, bsums, N, E);
  fill_k<<<eblk, blk, 0, stream>>>(edges, cur, bucket, E);

  // K1: xi = x @ W_aff^T + b_aff
  gemm_k<false, false, false, false><<<dim3(1, ny), blk, 0, stream>>>(
      x, nullptr, 0, W_aff, b_aff, xi, nullptr, nullptr, nullptr, N, 128, 128);

  // gather-reduce: aggs = segment_sum(x), aggm = segment_max(xi) (0 if empty)
  gather_k<<<(N + 1) / 2, blk, 0, stream>>>(off, bucket, x, xi, aggs, aggm, N);

  // K4/K5/K6 per node-chunk: gi, gh (bf16), GRU -> rnn (in place over aggm)
  for (int c = 0; c < C; c++) {
    int r0 = c * Nc;
    if (r0 >= N) break;
    int Nr = (N - r0 < Nc) ? (N - r0) : Nc;
    int nyc = (Nr + 127) / 128;
    gemm_k<false, true, false, false><<<dim3(3, nyc), blk, 0, stream>>>(
        aggm + (size_t)r0 * 128, nullptr, 0, W_ih, b_ih, nullptr, gi, nullptr,
        nullptr, Nr, 384, 128);
    gemm_k<false, true, false, false><<<dim3(3, nyc), blk, 0, stream>>>(
        x + (size_t)r0 * 128, nullptr, 0, W_hh, b_hh, nullptr, gh, nullptr,
        nullptr, Nr, 384, 128);
    gru_k<<<(Nr * 128 + 255) / 256, blk, 0, stream>>>(
        gi, gh, x + (size_t)r0 * 128, rnn + (size_t)r0 * 128, Nr * 128);
  }
  // K7: hpre = concat(aggs, rnn) @ W_merge^T + b_merge + eps*x
  gemm_k<false, false, true, true><<<dim3(1, ny), blk, 0, stream>>>(
      aggs, rnn, 128, W_merge, b_merge, hpre, nullptr, x, epsp, N, 128, 256);
  // K8: hid = relu(hpre @ W1^T + b1)
  gemm_k<true, false, false, false><<<dim3(2, ny), blk, 0, stream>>>(
      hpre, nullptr, 0, W1, b1, hid, nullptr, nullptr, nullptr, N, 256, 128);
  // K9: out = relu(hid @ W2^T + b2)
  gemm_k<true, false, false, false><<<dim3(1, ny), blk, 0, stream>>>(
      hid, nullptr, 0, W2, b2, out, nullptr, nullptr, nullptr, N, 128, 256);
  // K10-12: batchnorm
  bn_stats_k<<<512, blk, 0, stream>>>(out, stats, (int)nd);
  bn_final_k<<<1, 128, 0, stream>>>(stats, gamma, beta, N);
  bn_apply_k<<<(int)((nd / 4 + 255) / 256), blk, 0, stream>>>(
      out, stats + 256, stats + 384, (int)(nd / 4));
}

// Round 4
// 1055.105 us; speedup vs baseline: 7.2038x; 1.2128x over previous
//
#include <hip/hip_runtime.h>
#include <hip/hip_bf16.h>
#include <math.h>

using bf16 = __hip_bfloat16;
typedef __attribute__((ext_vector_type(8))) short bf16x8;
typedef __attribute__((ext_vector_type(4))) float f32x4;

__device__ __forceinline__ float b2f(unsigned short u) {
  return __uint_as_float(((unsigned)u) << 16);
}
__device__ __forceinline__ unsigned short f2b(float f) {
  bf16 h = __float2bfloat16(f);  // RNE
  return *reinterpret_cast<unsigned short*>(&h);
}

// ---------------------------------------------------------------------------
// MFMA bf16 GEMM: C[N,M] = A[N,K] @ W[M,K]^T + bias  (fp32 accumulate)
// Tile 128x128, BK=64, 256 threads = 4 waves, each wave 64x64 via 4x4 MFMA
// 16x16x32 fragments. A is bf16 (AF32=false) or fp32 converted in staging.
// W is fp32, converted in staging. Flags: RELU, OUTF32 (fp32 out else bf16),
// SPLIT (A = concat(A[:, :KA1], A2[:, KA1:K]), bf16 only), ADDX (+= eps*X).
// ---------------------------------------------------------------------------
template <bool AF32, bool RELU, bool OUTF32, bool SPLIT, bool ADDX>
__global__ __launch_bounds__(256) void mgemm_k(
    const void* __restrict__ Ap, const void* __restrict__ A2p, int KA1,
    const float* __restrict__ W, const float* __restrict__ bias,
    float* __restrict__ Cf, unsigned short* __restrict__ Cb,
    const float* __restrict__ X, const float* __restrict__ epsp,
    int N, int M, int K) {
  constexpr int BK = 64;
  constexpr int LDA = 72;  // bf16 elems per row (64 + 8 pad -> 144B stride)
  __shared__ unsigned short As[128 * LDA];
  __shared__ unsigned short Ws[128 * LDA];

  const int tid = threadIdx.x;
  const int lane = tid & 63;
  const int wave = tid >> 6;
  const int row0 = blockIdx.y * 128;
  const int m0 = blockIdx.x * 128;
  const int rowhalf = (wave & 1) * 64;
  const int colhalf = (wave >> 1) * 64;
  const int l15 = lane & 15;
  const int quad = lane >> 4;

  const float* Af = (const float*)Ap;
  const unsigned short* Ab = (const unsigned short*)Ap;
  const unsigned short* Ab2 = (const unsigned short*)A2p;

  f32x4 acc[4][4] = {};

  for (int kc = 0; kc < K; kc += BK) {
    // ---- stage A tile (128 x 64) into As as bf16 ----
    if (AF32) {
#pragma unroll
      for (int i = 0; i < 8; i++) {
        int idx = tid + i * 256;  // 0..2047 float4-groups
        int r = idx >> 4;         // 0..127
        int k4 = idx & 15;        // 0..15
        int row = row0 + r;
        float4 v = make_float4(0.f, 0.f, 0.f, 0.f);
        if (row < N) v = *(const float4*)(Af + (size_t)row * K + kc + k4 * 4);
        *(ushort4*)&As[r * LDA + k4 * 4] =
            make_ushort4(f2b(v.x), f2b(v.y), f2b(v.z), f2b(v.w));
      }
    } else {
#pragma unroll
      for (int i = 0; i < 4; i++) {
        int idx = tid + i * 256;  // 0..1023 groups of 8 bf16
        int r = idx >> 3;
        int k8 = idx & 7;
        int row = row0 + r;
        int kloc = kc + k8 * 8;
        ushort4 u0 = make_ushort4(0, 0, 0, 0), u1 = u0;
        if (row < N) {
          const unsigned short* s;
          if (SPLIT && kloc >= KA1)
            s = Ab2 + (size_t)row * (K - KA1) + (kloc - KA1);
          else
            s = Ab + (size_t)row * (SPLIT ? KA1 : K) + kloc;
          u0 = *(const ushort4*)s;
          u1 = *(const ushort4*)(s + 4);
        }
        *(ushort4*)&As[r * LDA + k8 * 8] = u0;
        *(ushort4*)&As[r * LDA + k8 * 8 + 4] = u1;
      }
    }
    // ---- stage W tile (128 x 64) into Ws as bf16 (M multiple of 128) ----
#pragma unroll
    for (int i = 0; i < 8; i++) {
      int idx = tid + i * 256;
      int r = idx >> 4;
      int k4 = idx & 15;
      float4 v = *(const float4*)(W + (size_t)(m0 + r) * K + kc + k4 * 4);
      *(ushort4*)&Ws[r * LDA + k4 * 4] =
          make_ushort4(f2b(v.x), f2b(v.y), f2b(v.z), f2b(v.w));
    }
    __syncthreads();
    // ---- MFMA: 2 k-steps of 32, 4x4 fragment tiles per wave ----
#pragma unroll
    for (int ks = 0; ks < BK / 32; ks++) {
      const int ko = ks * 32 + quad * 8;
      bf16x8 af[4], wf[4];
#pragma unroll
      for (int ri = 0; ri < 4; ri++)
        af[ri] = *(const bf16x8*)&As[(rowhalf + ri * 16 + l15) * LDA + ko];
#pragma unroll
      for (int ci = 0; ci < 4; ci++)
        wf[ci] = *(const bf16x8*)&Ws[(colhalf + ci * 16 + l15) * LDA + ko];
#pragma unroll
      for (int ri = 0; ri < 4; ri++)
#pragma unroll
        for (int ci = 0; ci < 4; ci++)
          acc[ri][ci] = __builtin_amdgcn_mfma_f32_16x16x32_bf16(
              af[ri], wf[ci], acc[ri][ci], 0, 0, 0);
    }
    __syncthreads();
  }

  // ---- epilogue: C/D layout col=lane&15, row=quad*4+reg ----
  const float ep = ADDX ? epsp[0] : 0.f;
#pragma unroll
  for (int ci = 0; ci < 4; ci++) {
    const int col = m0 + colhalf + ci * 16 + l15;
    const float bv = bias[col];
#pragma unroll
    for (int ri = 0; ri < 4; ri++) {
      const int rbase = row0 + rowhalf + ri * 16 + quad * 4;
#pragma unroll
      for (int r = 0; r < 4; r++) {
        int row = rbase + r;
        if (row >= N) continue;
        float v = acc[ri][ci][r] + bv;
        if (ADDX) v += ep * X[(size_t)row * M + col];
        if (RELU) v = fmaxf(v, 0.f);
        if (OUTF32)
          Cf[(size_t)row * M + col] = v;
        else
          Cb[(size_t)row * M + col] = f2b(v);
      }
    }
  }
}

// ---------------------------------------------------------------------------
// CSR build: zero deg+stats; histogram by dst; block scan; fill buckets.
// ---------------------------------------------------------------------------
__global__ __launch_bounds__(256) void init0_k(int* __restrict__ deg,
                                               float* __restrict__ stats,
                                               int N) {
  int i = blockIdx.x * 256 + threadIdx.x;
  if (i < N) deg[i] = 0;
  if (blockIdx.x == 0) stats[threadIdx.x] = 0.f;
  if (blockIdx.x == 1) stats[256 + threadIdx.x] = 0.f;
}

__global__ __launch_bounds__(256) void hist_k(const int* __restrict__ edges,
                                              int* __restrict__ deg, int E) {
  int e = blockIdx.x * 256 + threadIdx.x;
  if (e < E) atomicAdd(&deg[edges[(size_t)E + e]], 1);
}

__global__ __launch_bounds__(256) void scan1_k(const int* __restrict__ deg,
                                               int* __restrict__ off,
                                               int* __restrict__ bsums, int N) {
  __shared__ int s[256];
  int t = threadIdx.x;
  int i = blockIdx.x * 256 + t;
  int v = (i < N) ? deg[i] : 0;
  s[t] = v;
  __syncthreads();
#pragma unroll
  for (int d = 1; d < 256; d <<= 1) {
    int u = (t >= d) ? s[t - d] : 0;
    __syncthreads();
    s[t] += u;
    __syncthreads();
  }
  if (i < N) off[i] = s[t] - v;
  if (t == 255) bsums[blockIdx.x] = s[255];
}

__global__ __launch_bounds__(512) void scan2_k(int* __restrict__ bsums,
                                               int nb) {
  __shared__ int s[512];
  int t = threadIdx.x;
  int v = (t < nb) ? bsums[t] : 0;
  s[t] = v;
  __syncthreads();
#pragma unroll
  for (int d = 1; d < 512; d <<= 1) {
    int u = (t >= d) ? s[t - d] : 0;
    __syncthreads();
    s[t] += u;
    __syncthreads();
  }
  if (t < nb) bsums[t] = s[t] - v;
}

__global__ __launch_bounds__(256) void scan3_k(int* __restrict__ off,
                                               int* __restrict__ cur,
                                               const int* __restrict__ bsums,
                                               int N, int E) {
  int i = blockIdx.x * 256 + threadIdx.x;
  if (i < N) {
    int o = off[i] + bsums[blockIdx.x];
    off[i] = o;
    cur[i] = o;
  }
  if (i == 0) off[N] = E;
}

__global__ __launch_bounds__(256) void fill_k(const int* __restrict__ edges,
                                              int* __restrict__ cur,
                                              int* __restrict__ bucket, int E) {
  int e = blockIdx.x * 256 + threadIdx.x;
  if (e >= E) return;
  int src = edges[e];
  int dst = edges[(size_t)E + e];
  int pos = atomicAdd(&cur[dst], 1);
  bucket[pos] = src;
}

// ---------------------------------------------------------------------------
// gather-reduce: 128 threads/node (one per feature), 2 nodes/block.
// aggs = bf16(segment_sum(x)), aggm = bf16(segment_max(xib)) (0 if empty).
// ---------------------------------------------------------------------------
__global__ __launch_bounds__(256) void gather_k(
    const int* __restrict__ off, const int* __restrict__ bucket,
    const float* __restrict__ x, const unsigned short* __restrict__ xib,
    unsigned short* __restrict__ aggs, unsigned short* __restrict__ aggm,
    int N) {
  int node = blockIdx.x * 2 + (threadIdx.x >> 7);
  int f = threadIdx.x & 127;
  if (node >= N) return;
  int j0 = off[node], jend = off[node + 1];
  float s = 0.f, m = -INFINITY;
  for (int j = j0; j < jend; j++) {
    int src = bucket[j];
    size_t b = (size_t)src * 128 + f;
    s += x[b];
    m = fmaxf(m, b2f(xib[b]));
  }
  size_t o = (size_t)node * 128 + f;
  aggs[o] = f2b(s);
  aggm[o] = (jend > j0) ? f2b(m) : (unsigned short)0;  // max of bf16: exact
}

// ---------------------------------------------------------------------------
// GRU elementwise (4 features/thread): rnn = (1-z)*tanh(inn + r*hn) + z*x
// ---------------------------------------------------------------------------
__global__ __launch_bounds__(256) void gru4_k(
    const unsigned short* __restrict__ gi, const unsigned short* __restrict__ gh,
    const float* __restrict__ x, unsigned short* __restrict__ rnn,
    int ngroups) {
  int g = blockIdx.x * 256 + threadIdx.x;
  if (g >= ngroups) return;
  int n = g >> 5;
  int j = (g & 31) * 4;
  size_t b = (size_t)n * 384 + j;
  ushort4 vir = *(const ushort4*)&gi[b];
  ushort4 viz = *(const ushort4*)&gi[b + 128];
  ushort4 vin = *(const ushort4*)&gi[b + 256];
  ushort4 vhr = *(const ushort4*)&gh[b];
  ushort4 vhz = *(const ushort4*)&gh[b + 128];
  ushort4 vhn = *(const ushort4*)&gh[b + 256];
  float4 xv = *(const float4*)&x[(size_t)n * 128 + j];
  const unsigned short ir[4] = {vir.x, vir.y, vir.z, vir.w};
  const unsigned short iz[4] = {viz.x, viz.y, viz.z, viz.w};
  const unsigned short in_[4] = {vin.x, vin.y, vin.z, vin.w};
  const unsigned short hr[4] = {vhr.x, vhr.y, vhr.z, vhr.w};
  const unsigned short hz[4] = {vhz.x, vhz.y, vhz.z, vhz.w};
  const unsigned short hn[4] = {vhn.x, vhn.y, vhn.z, vhn.w};
  const float xs[4] = {xv.x, xv.y, xv.z, xv.w};
  unsigned short o[4];
#pragma unroll
  for (int i = 0; i < 4; i++) {
    float r = 1.f / (1.f + __expf(-(b2f(ir[i]) + b2f(hr[i]))));
    float z = 1.f / (1.f + __expf(-(b2f(iz[i]) + b2f(hz[i]))));
    float nc = tanhf(b2f(in_[i]) + r * b2f(hn[i]));
    o[i] = f2b((1.f - z) * nc + z * xs[i]);
  }
  *(ushort4*)&rnn[(size_t)n * 128 + j] = make_ushort4(o[0], o[1], o[2], o[3]);
}

// ---------------------------------------------------------------------------
// BatchNorm: stats (sum, sumsq per channel), finalize, apply (in-place)
// ---------------------------------------------------------------------------
__global__ __launch_bounds__(256) void bn_stats_k(const float* __restrict__ h,
                                                  float* __restrict__ stats,
                                                  int total) {
  float s = 0.f, q = 0.f;
  for (int g = blockIdx.x * 256 + threadIdx.x; g < total;
       g += gridDim.x * 256) {
    float v = h[g];
    s += v;
    q += v * v;
  }
  __shared__ float ls[256], lq[256];
  int tid = threadIdx.x;
  ls[tid] = s;
  lq[tid] = q;
  __syncthreads();
  if (tid < 128) {
    atomicAdd(&stats[tid], ls[tid] + ls[tid + 128]);
    atomicAdd(&stats[128 + tid], lq[tid] + lq[tid + 128]);
  }
}

__global__ void bn_final_k(float* __restrict__ stats,
                           const float* __restrict__ gamma,
                           const float* __restrict__ beta, int N) {
  int d = threadIdx.x;
  if (d >= 128) return;
  float invn = 1.f / (float)N;
  float mean = stats[d] * invn;
  float var = stats[128 + d] * invn - mean * mean;
  var = fmaxf(var, 0.f);
  float sc = gamma[d] * rsqrtf(var + 1e-5f);
  stats[256 + d] = sc;
  stats[384 + d] = beta[d] - mean * sc;
}

__global__ __launch_bounds__(256) void bn_apply_k(float* __restrict__ out,
                                                  const float* __restrict__ sc,
                                                  const float* __restrict__ sh,
                                                  int nd4) {
  int g = blockIdx.x * 256 + threadIdx.x;
  if (g >= nd4) return;
  float4 v = ((float4*)out)[g];
  int d = (g & 31) * 4;
  v.x = v.x * sc[d + 0] + sh[d + 0];
  v.y = v.y * sc[d + 1] + sh[d + 1];
  v.z = v.z * sc[d + 2] + sh[d + 2];
  v.w = v.w * sc[d + 3] + sh[d + 3];
  ((float4*)out)[g] = v;
}

// ---------------------------------------------------------------------------
extern "C" void kernel_launch(void* const* d_in, const int* in_sizes, int n_in,
                              void* d_out, int out_size, void* d_ws,
                              size_t ws_size, hipStream_t stream) {
  (void)n_in;
  (void)out_size;
  const float* x = (const float*)d_in[0];
  const int* edges = (const int*)d_in[1];
  const float* W_aff = (const float*)d_in[2];
  const float* b_aff = (const float*)d_in[3];
  const float* W_ih = (const float*)d_in[4];
  const float* b_ih = (const float*)d_in[5];
  const float* W_hh = (const float*)d_in[6];
  const float* b_hh = (const float*)d_in[7];
  const float* W_merge = (const float*)d_in[8];
  const float* b_merge = (const float*)d_in[9];
  const float* epsp = (const float*)d_in[10];
  const float* W1 = (const float*)d_in[11];
  const float* b1 = (const float*)d_in[12];
  const float* W2 = (const float*)d_in[13];
  const float* b2 = (const float*)d_in[14];
  const float* gamma = (const float*)d_in[15];
  const float* beta = (const float*)d_in[16];

  const int N = in_sizes[0] / 128;
  const int E = in_sizes[1] / 2;
  const size_t nd = (size_t)N * 128;

  // ---- workspace plan (all activations bf16) ----
  //  [0,      N*256)  aggm -> rnn (in place); with aggs forms hid (N*512)
  //  [N*256,  N*512)  aggs
  //  [N*512,  N*768)  xib -> hpre
  //  [N*768,  +2*Nc*768)  gi | gh  (bf16, chunked over node ranges)
  //  [..,     +2048)      stats[512]
  //  [..,     +CSR)       deg[N], off[N+1], cur[N], bucket[E], bsums[512]
  const size_t csr_bytes = ((size_t)3 * N + 1 + E + 512) * 4;
  int C = 50;
  const int cand[] = {1, 2, 4, 5, 8, 10, 20, 25, 50};
  for (int ci = 0; ci < 9; ci++) {
    int c = cand[ci];
    int nc = (N + c - 1) / c;
    size_t need = (size_t)N * 768 + (size_t)2 * nc * 768 + 2048 + csr_bytes;
    if (need <= ws_size) {
      C = c;
      break;
    }
  }
  const int Nc = (N + C - 1) / C;

  char* base = (char*)d_ws;
  unsigned short* aggm = (unsigned short*)base;
  unsigned short* rnn = aggm;
  unsigned short* aggs = (unsigned short*)(base + (size_t)N * 256);
  unsigned short* xib = (unsigned short*)(base + (size_t)N * 512);
  unsigned short* hpre = xib;
  unsigned short* hid = (unsigned short*)base;  // N*512 B over aggm+aggs (dead)
  unsigned short* gi = (unsigned short*)(base + (size_t)N * 768);
  unsigned short* gh = gi + (size_t)Nc * 384;
  float* stats = (float*)(base + (size_t)N * 768 + (size_t)2 * Nc * 768);
  int* deg = (int*)(stats + 512);
  int* off = deg + N;
  int* cur = off + N + 1;
  int* bucket = cur + N;
  int* bsums = bucket + E;
  float* out = (float*)d_out;

  const int ny = (N + 127) / 128;
  const int nblk = (N + 255) / 256;
  const int eblk = (E + 255) / 256;
  dim3 blk(256);

  // ---- CSR build ----
  init0_k<<<nblk, blk, 0, stream>>>(deg, stats, N);
  hist_k<<<eblk, blk, 0, stream>>>(edges, deg, E);
  scan1_k<<<nblk, blk, 0, stream>>>(deg, off, bsums, N);
  scan2_k<<<1, 512, 0, stream>>>(bsums, nblk);
  scan3_k<<<nblk, blk, 0, stream>>>(off, cur, bsums, N, E);
  fill_k<<<eblk, blk, 0, stream>>>(edges, cur, bucket, E);

  // xib = bf16(x @ W_aff^T + b_aff)
  mgemm_k<true, false, false, false, false><<<dim3(1, ny), blk, 0, stream>>>(
      x, nullptr, 0, W_aff, b_aff, nullptr, xib, nullptr, nullptr, N, 128, 128);

  // gather-reduce
  gather_k<<<(N + 1) / 2, blk, 0, stream>>>(off, bucket, x, xib, aggs, aggm, N);

  // per node-chunk: gi = aggm @ W_ih^T, gh = x @ W_hh^T, GRU -> rnn (bf16)
  for (int c = 0; c < C; c++) {
    int r0 = c * Nc;
    if (r0 >= N) break;
    int Nr = (N - r0 < Nc) ? (N - r0) : Nc;
    int nyc = (Nr + 127) / 128;
    mgemm_k<false, false, false, false, false>
        <<<dim3(3, nyc), blk, 0, stream>>>(aggm + (size_t)r0 * 128, nullptr, 0,
                                           W_ih, b_ih, nullptr, gi, nullptr,
                                           nullptr, Nr, 384, 128);
    mgemm_k<true, false, false, false, false>
        <<<dim3(3, nyc), blk, 0, stream>>>(x + (size_t)r0 * 128, nullptr, 0,
                                           W_hh, b_hh, nullptr, gh, nullptr,
                                           nullptr, Nr, 384, 128);
    gru4_k<<<(Nr * 32 + 255) / 256, blk, 0, stream>>>(
        gi, gh, x + (size_t)r0 * 128, rnn + (size_t)r0 * 128, Nr * 32);
  }
  // hpre = bf16(concat(aggs, rnn) @ W_merge^T + b_merge + eps*x)
  mgemm_k<false, false, false, true, true><<<dim3(1, ny), blk, 0, stream>>>(
      aggs, rnn, 128, W_merge, b_merge, nullptr, hpre, x, epsp, N, 128, 256);
  // hid = bf16(relu(hpre @ W1^T + b1))
  mgemm_k<false, true, false, false, false><<<dim3(2, ny), blk, 0, stream>>>(
      hpre, nullptr, 0, W1, b1, nullptr, hid, nullptr, nullptr, N, 256, 128);
  // out = relu(hid @ W2^T + b2)  (fp32)
  mgemm_k<false, true, true, false, false><<<dim3(1, ny), blk, 0, stream>>>(
      hid, nullptr, 0, W2, b2, out, nullptr, nullptr, nullptr, N, 128, 256);
  // batchnorm
  bn_stats_k<<<512, blk, 0, stream>>>(out, stats, (int)nd);
  bn_final_k<<<1, 128, 0, stream>>>(stats, gamma, beta, N);
  bn_apply_k<<<(int)((nd / 4 + 255) / 256), blk, 0, stream>>>(
      out, stats + 256, stats + 384, (int)(nd / 4));
}

// Round 5
// 879.060 us; speedup vs baseline: 8.6464x; 1.2003x over previous
//
#include <hip/hip_runtime.h>
#include <hip/hip_bf16.h>
#include <math.h>

using bf16 = __hip_bfloat16;
typedef __attribute__((ext_vector_type(8))) short bf16x8;
typedef __attribute__((ext_vector_type(4))) float f32x4;

__device__ __forceinline__ float b2f(unsigned short u) {
  return __uint_as_float(((unsigned)u) << 16);
}
__device__ __forceinline__ unsigned short f2b(float f) {
  bf16 h = __float2bfloat16(f);  // RNE
  return *reinterpret_cast<unsigned short*>(&h);
}

// ---------------------------------------------------------------------------
// MFMA bf16 GEMM: C[N,M] = A[N,K] @ W[M,K]^T + bias  (fp32 accumulate)
// A bf16 row stride lda; W fp32 (converted in staging). Tile 128x128, BK=64,
// 256 threads = 4 waves (wave = 64x64 via 4x4 16x16x32 fragments).
// Flags: RELU, OUTF32 (fp32 out, else bf16), ADDX (C += eps*X, X fp32 NxM).
// ---------------------------------------------------------------------------
template <bool RELU, bool OUTF32, bool ADDX>
__global__ __launch_bounds__(256) void mgemm_k(
    const unsigned short* __restrict__ A, int lda,
    const float* __restrict__ W, const float* __restrict__ bias,
    float* __restrict__ Cf, unsigned short* __restrict__ Cb,
    const float* __restrict__ X, const float* __restrict__ epsp,
    int N, int M, int K) {
  constexpr int BK = 64;
  constexpr int LDA = 72;  // ushorts per row (64 + 8 pad)
  __shared__ unsigned short As[128 * LDA];
  __shared__ unsigned short Ws[128 * LDA];

  const int tid = threadIdx.x;
  const int lane = tid & 63;
  const int wave = tid >> 6;
  const int row0 = blockIdx.y * 128;
  const int m0 = blockIdx.x * 128;
  const int rowhalf = (wave & 1) * 64;
  const int colhalf = (wave >> 1) * 64;
  const int l15 = lane & 15;
  const int quad = lane >> 4;

  f32x4 acc[4][4] = {};

  for (int kc = 0; kc < K; kc += BK) {
    // stage A (128 x 64 bf16)
#pragma unroll
    for (int i = 0; i < 4; i++) {
      int idx = tid + i * 256;
      int r = idx >> 3;
      int k8 = (idx & 7) * 8;
      int row = row0 + r;
      ushort4 u0 = make_ushort4(0, 0, 0, 0), u1 = u0;
      if (row < N) {
        const unsigned short* s = A + (size_t)row * lda + kc + k8;
        u0 = *(const ushort4*)s;
        u1 = *(const ushort4*)(s + 4);
      }
      *(ushort4*)&As[r * LDA + k8] = u0;
      *(ushort4*)&As[r * LDA + k8 + 4] = u1;
    }
    // stage W (128 x 64 fp32 -> bf16); M multiple of 128
#pragma unroll
    for (int i = 0; i < 8; i++) {
      int idx = tid + i * 256;
      int r = idx >> 4;
      int k4 = idx & 15;
      float4 v = *(const float4*)(W + (size_t)(m0 + r) * K + kc + k4 * 4);
      *(ushort4*)&Ws[r * LDA + k4 * 4] =
          make_ushort4(f2b(v.x), f2b(v.y), f2b(v.z), f2b(v.w));
    }
    __syncthreads();
#pragma unroll
    for (int ks = 0; ks < BK / 32; ks++) {
      const int ko = ks * 32 + quad * 8;
      bf16x8 af[4], wf[4];
#pragma unroll
      for (int ri = 0; ri < 4; ri++)
        af[ri] = *(const bf16x8*)&As[(rowhalf + ri * 16 + l15) * LDA + ko];
#pragma unroll
      for (int ci = 0; ci < 4; ci++)
        wf[ci] = *(const bf16x8*)&Ws[(colhalf + ci * 16 + l15) * LDA + ko];
#pragma unroll
      for (int ri = 0; ri < 4; ri++)
#pragma unroll
        for (int ci = 0; ci < 4; ci++)
          acc[ri][ci] = __builtin_amdgcn_mfma_f32_16x16x32_bf16(
              af[ri], wf[ci], acc[ri][ci], 0, 0, 0);
    }
    __syncthreads();
  }

  const float ep = ADDX ? epsp[0] : 0.f;
#pragma unroll
  for (int ci = 0; ci < 4; ci++) {
    const int col = m0 + colhalf + ci * 16 + l15;
    const float bv = bias[col];
#pragma unroll
    for (int ri = 0; ri < 4; ri++) {
      const int rbase = row0 + rowhalf + ri * 16 + quad * 4;
#pragma unroll
      for (int r = 0; r < 4; r++) {
        int row = rbase + r;
        if (row >= N) continue;
        float v = acc[ri][ci][r] + bv;
        if (ADDX) v += ep * X[(size_t)row * M + col];
        if (RELU) v = fmaxf(v, 0.f);
        if (OUTF32)
          Cf[(size_t)row * M + col] = v;
        else
          Cb[(size_t)row * M + col] = f2b(v);
      }
    }
  }
}

// ---------------------------------------------------------------------------
// Fused GRU-GEMM: G[N,512] = Acat[N,256] @ Wbig[512,256]^T, gates through
// LDS, GRU nonlinearity, rnn -> Bcat[:,128:256]. Block = 32 rows, 4 waves;
// wave w computes gate col-slice [w*128,(w+1)*128). Wbig bf16 read from L2.
// ---------------------------------------------------------------------------
__global__ __launch_bounds__(256) void grurnn_k(
    const unsigned short* __restrict__ Acat,
    const unsigned short* __restrict__ Wbig,
    const float* __restrict__ bias_big, const float* __restrict__ x,
    unsigned short* __restrict__ Bcat, int N) {
  constexpr int LDA = 72;
  constexpr int LDE = 520;  // 512 + 8 pad
  __shared__ unsigned short As[32 * LDA];
  __shared__ unsigned short Ex[32 * LDE];

  const int tid = threadIdx.x;
  const int lane = tid & 63;
  const int wave = tid >> 6;
  const int l15 = lane & 15;
  const int quad = lane >> 4;
  const int row0 = blockIdx.x * 32;

  f32x4 acc[2][8] = {};

  for (int kc = 0; kc < 256; kc += 64) {
    {  // stage A (32 x 64)
      int r = tid >> 3;
      int k8 = (tid & 7) * 8;
      int row = row0 + r;
      ushort4 u0 = make_ushort4(0, 0, 0, 0), u1 = u0;
      if (row < N) {
        const unsigned short* s = Acat + (size_t)row * 256 + kc + k8;
        u0 = *(const ushort4*)s;
        u1 = *(const ushort4*)(s + 4);
      }
      *(ushort4*)&As[r * LDA + k8] = u0;
      *(ushort4*)&As[r * LDA + k8 + 4] = u1;
    }
    __syncthreads();
#pragma unroll
    for (int ks = 0; ks < 2; ks++) {
      const int ko = ks * 32 + quad * 8;
      bf16x8 af[2];
#pragma unroll
      for (int ri = 0; ri < 2; ri++)
        af[ri] = *(const bf16x8*)&As[(ri * 16 + l15) * LDA + ko];
#pragma unroll
      for (int ci = 0; ci < 8; ci++) {
        int m = wave * 128 + ci * 16 + l15;
        bf16x8 wf = *(const bf16x8*)&Wbig[(size_t)m * 256 + kc + ko];
#pragma unroll
        for (int ri = 0; ri < 2; ri++)
          acc[ri][ci] = __builtin_amdgcn_mfma_f32_16x16x32_bf16(
              af[ri], wf, acc[ri][ci], 0, 0, 0);
      }
    }
    __syncthreads();
  }
  // gates -> LDS (bf16)
#pragma unroll
  for (int ci = 0; ci < 8; ci++) {
    const int col = wave * 128 + ci * 16 + l15;
#pragma unroll
    for (int ri = 0; ri < 2; ri++) {
      const int rb = ri * 16 + quad * 4;
#pragma unroll
      for (int r = 0; r < 4; r++) Ex[(rb + r) * LDE + col] = f2b(acc[ri][ci][r]);
    }
  }
  __syncthreads();
  // GRU nonlinearity: 8 items/thread, 2 features each
#pragma unroll
  for (int it = 0; it < 8; it++) {
    int idx = tid + it * 256;
    int r = idx >> 6;
    int f = (idx & 63) * 2;
    int row = row0 + r;
    if (row >= N) continue;
    ushort2 usr = *(ushort2*)&Ex[r * LDE + f];
    ushort2 usz = *(ushort2*)&Ex[r * LDE + 128 + f];
    ushort2 usi = *(ushort2*)&Ex[r * LDE + 256 + f];
    ushort2 ush = *(ushort2*)&Ex[r * LDE + 384 + f];
    float2 br = *(const float2*)&bias_big[f];
    float2 bz = *(const float2*)&bias_big[128 + f];
    float2 bi = *(const float2*)&bias_big[256 + f];
    float2 bh = *(const float2*)&bias_big[384 + f];
    float2 xv = *(const float2*)&x[(size_t)row * 128 + f];
    float rg0 = 1.f / (1.f + __expf(-(b2f(usr.x) + br.x)));
    float rg1 = 1.f / (1.f + __expf(-(b2f(usr.y) + br.y)));
    float zg0 = 1.f / (1.f + __expf(-(b2f(usz.x) + bz.x)));
    float zg1 = 1.f / (1.f + __expf(-(b2f(usz.y) + bz.y)));
    float nc0 = tanhf(b2f(usi.x) + bi.x + rg0 * (b2f(ush.x) + bh.x));
    float nc1 = tanhf(b2f(usi.y) + bi.y + rg1 * (b2f(ush.y) + bh.y));
    float o0 = (1.f - zg0) * nc0 + zg0 * xv.x;
    float o1 = (1.f - zg1) * nc1 + zg1 * xv.y;
    *(ushort2*)&Bcat[(size_t)row * 256 + 128 + f] =
        make_ushort2(f2b(o0), f2b(o1));
  }
}

// ---------------------------------------------------------------------------
// prep: build Wbig (bf16 512x256) + bias_big + zero stats
// ---------------------------------------------------------------------------
__global__ __launch_bounds__(256) void prep_k(
    const float* __restrict__ W_ih, const float* __restrict__ b_ih,
    const float* __restrict__ W_hh, const float* __restrict__ b_hh,
    unsigned short* __restrict__ Wbig, float* __restrict__ bias_big,
    float* __restrict__ stats) {
  int idx = blockIdx.x * 256 + threadIdx.x;  // 128 blocks -> 32768
  int m = idx >> 6;
  int k4 = (idx & 63) * 4;
  const float* src = nullptr;
  int koff = 0;
  if (m < 256) {
    if (k4 < 128) { src = W_ih + (size_t)m * 128; koff = k4; }
    else          { src = W_hh + (size_t)m * 128; koff = k4 - 128; }
  } else if (m < 384) {
    if (k4 < 128) { src = W_ih + (size_t)m * 128; koff = k4; }
  } else {
    if (k4 >= 128) { src = W_hh + (size_t)(m - 128) * 128; koff = k4 - 128; }
  }
  ushort4 o = make_ushort4(0, 0, 0, 0);
  if (src) {
    float4 v = *(const float4*)(src + koff);
    o = make_ushort4(f2b(v.x), f2b(v.y), f2b(v.z), f2b(v.w));
  }
  *(ushort4*)&Wbig[(size_t)m * 256 + k4] = o;
  if (blockIdx.x == 0) {
    int t = threadIdx.x;
    stats[t] = 0.f;
#pragma unroll
    for (int h = 0; h < 2; h++) {
      int mm = t + h * 256;
      float b;
      if (mm < 256) b = b_ih[mm] + b_hh[mm];
      else if (mm < 384) b = b_ih[mm];
      else b = b_hh[mm - 128];
      bias_big[mm] = b;
    }
  }
}

// ---------------------------------------------------------------------------
// CSR build
// ---------------------------------------------------------------------------
__global__ __launch_bounds__(256) void init0_k(int* __restrict__ deg, int N) {
  int i = blockIdx.x * 256 + threadIdx.x;
  if (i < N) deg[i] = 0;
}

__global__ __launch_bounds__(256) void hist_k(const int* __restrict__ edges,
                                              int* __restrict__ deg, int E) {
  int e = blockIdx.x * 256 + threadIdx.x;
  if (e < E) atomicAdd(&deg[edges[(size_t)E + e]], 1);
}

__global__ __launch_bounds__(256) void scan1_k(const int* __restrict__ deg,
                                               int* __restrict__ off,
                                               int* __restrict__ bsums, int N) {
  __shared__ int s[256];
  int t = threadIdx.x;
  int i = blockIdx.x * 256 + t;
  int v = (i < N) ? deg[i] : 0;
  s[t] = v;
  __syncthreads();
#pragma unroll
  for (int d = 1; d < 256; d <<= 1) {
    int u = (t >= d) ? s[t - d] : 0;
    __syncthreads();
    s[t] += u;
    __syncthreads();
  }
  if (i < N) off[i] = s[t] - v;
  if (t == 255) bsums[blockIdx.x] = s[255];
}

__global__ __launch_bounds__(512) void scan2_k(int* __restrict__ bsums,
                                               int nb) {
  __shared__ int s[512];
  int t = threadIdx.x;
  int v = (t < nb) ? bsums[t] : 0;
  s[t] = v;
  __syncthreads();
#pragma unroll
  for (int d = 1; d < 512; d <<= 1) {
    int u = (t >= d) ? s[t - d] : 0;
    __syncthreads();
    s[t] += u;
    __syncthreads();
  }
  if (t < nb) bsums[t] = s[t] - v;
}

__global__ __launch_bounds__(256) void scan3_k(int* __restrict__ off,
                                               int* __restrict__ cur,
                                               const int* __restrict__ bsums,
                                               int N, int E) {
  int i = blockIdx.x * 256 + threadIdx.x;
  if (i < N) {
    int o = off[i] + bsums[blockIdx.x];
    off[i] = o;
    cur[i] = o;
  }
  if (i == 0) off[N] = E;
}

__global__ __launch_bounds__(256) void fill_k(const int* __restrict__ edges,
                                              int* __restrict__ cur,
                                              int* __restrict__ bucket, int E) {
  int e = blockIdx.x * 256 + threadIdx.x;
  if (e >= E) return;
  int src = edges[e];
  int dst = edges[(size_t)E + e];
  int pos = atomicAdd(&cur[dst], 1);
  bucket[pos] = src;
}

// ---------------------------------------------------------------------------
// cvt: x fp32 -> bf16 into Acat right half (row stride 256)
// ---------------------------------------------------------------------------
__global__ __launch_bounds__(256) void cvt_k(const float* __restrict__ x,
                                             unsigned short* __restrict__ Acat,
                                             int ngroups) {
  int g = blockIdx.x * 256 + threadIdx.x;
  if (g >= ngroups) return;
  int n = g >> 5;
  int j = (g & 31) * 4;
  float4 v = *(const float4*)&x[(size_t)n * 128 + j];
  *(ushort4*)&Acat[(size_t)n * 256 + 128 + j] =
      make_ushort4(f2b(v.x), f2b(v.y), f2b(v.z), f2b(v.w));
}

// ---------------------------------------------------------------------------
// gather-reduce: one wave per node, 2 features/lane (float2 + ushort2),
// depth-2 index prefetch. aggm -> Acat[:,0:128], aggs -> Bcat[:,0:128].
// ---------------------------------------------------------------------------
__global__ __launch_bounds__(256) void gather_k(
    const int* __restrict__ off, const int* __restrict__ bucket,
    const float* __restrict__ x, const unsigned short* __restrict__ xib,
    unsigned short* __restrict__ Acat, unsigned short* __restrict__ Bcat,
    int N) {
  int node = blockIdx.x * 4 + (threadIdx.x >> 6);
  if (node >= N) return;
  int f = (threadIdx.x & 63) * 2;
  int j0 = off[node], jend = off[node + 1];
  float s0 = 0.f, s1 = 0.f, m0 = -INFINITY, m1 = -INFINITY;
  int p0 = (j0 < jend) ? bucket[j0] : 0;
  int p1 = (j0 + 1 < jend) ? bucket[j0 + 1] : 0;
  for (int j = j0; j < jend; j++) {
    int src = p0;
    p0 = p1;
    p1 = (j + 2 < jend) ? bucket[j + 2] : 0;
    float2 xv = *(const float2*)(x + (size_t)src * 128 + f);
    ushort2 uv = *(const ushort2*)(xib + (size_t)src * 128 + f);
    s0 += xv.x;
    s1 += xv.y;
    m0 = fmaxf(m0, b2f(uv.x));
    m1 = fmaxf(m1, b2f(uv.y));
  }
  bool nz = jend > j0;
  size_t o = (size_t)node * 256 + f;
  *(ushort2*)&Acat[o] =
      make_ushort2(nz ? f2b(m0) : (unsigned short)0,
                   nz ? f2b(m1) : (unsigned short)0);
  *(ushort2*)&Bcat[o] = make_ushort2(f2b(s0), f2b(s1));
}

// ---------------------------------------------------------------------------
// BatchNorm
// ---------------------------------------------------------------------------
__global__ __launch_bounds__(256) void bn_stats_k(const float* __restrict__ h,
                                                  float* __restrict__ stats,
                                                  int total) {
  float s = 0.f, q = 0.f;
  for (int g = blockIdx.x * 256 + threadIdx.x; g < total;
       g += gridDim.x * 256) {
    float v = h[g];
    s += v;
    q += v * v;
  }
  __shared__ float ls[256], lq[256];
  int tid = threadIdx.x;
  ls[tid] = s;
  lq[tid] = q;
  __syncthreads();
  if (tid < 128) {
    atomicAdd(&stats[tid], ls[tid] + ls[tid + 128]);
    atomicAdd(&stats[128 + tid], lq[tid] + lq[tid + 128]);
  }
}

__global__ void bn_final_k(float* __restrict__ stats,
                           const float* __restrict__ gamma,
                           const float* __restrict__ beta, int N) {
  int d = threadIdx.x;
  if (d >= 128) return;
  float invn = 1.f / (float)N;
  float mean = stats[d] * invn;
  float var = stats[128 + d] * invn - mean * mean;
  var = fmaxf(var, 0.f);
  float sc = gamma[d] * rsqrtf(var + 1e-5f);
  stats[256 + d] = sc;
  stats[384 + d] = beta[d] - mean * sc;
}

__global__ __launch_bounds__(256) void bn_apply_k(float* __restrict__ out,
                                                  const float* __restrict__ sc,
                                                  const float* __restrict__ sh,
                                                  int nd4) {
  int g = blockIdx.x * 256 + threadIdx.x;
  if (g >= nd4) return;
  float4 v = ((float4*)out)[g];
  int d = (g & 31) * 4;
  v.x = v.x * sc[d + 0] + sh[d + 0];
  v.y = v.y * sc[d + 1] + sh[d + 1];
  v.z = v.z * sc[d + 2] + sh[d + 2];
  v.w = v.w * sc[d + 3] + sh[d + 3];
  ((float4*)out)[g] = v;
}

// ---------------------------------------------------------------------------
extern "C" void kernel_launch(void* const* d_in, const int* in_sizes, int n_in,
                              void* d_out, int out_size, void* d_ws,
                              size_t ws_size, hipStream_t stream) {
  (void)n_in;
  (void)out_size;
  (void)ws_size;
  const float* x = (const float*)d_in[0];
  const int* edges = (const int*)d_in[1];
  const float* W_aff = (const float*)d_in[2];
  const float* b_aff = (const float*)d_in[3];
  const float* W_ih = (const float*)d_in[4];
  const float* b_ih = (const float*)d_in[5];
  const float* W_hh = (const float*)d_in[6];
  const float* b_hh = (const float*)d_in[7];
  const float* W_merge = (const float*)d_in[8];
  const float* b_merge = (const float*)d_in[9];
  const float* epsp = (const float*)d_in[10];
  const float* W1 = (const float*)d_in[11];
  const float* b1 = (const float*)d_in[12];
  const float* W2 = (const float*)d_in[13];
  const float* b2 = (const float*)d_in[14];
  const float* gamma = (const float*)d_in[15];
  const float* beta = (const float*)d_in[16];

  const int N = in_sizes[0] / 128;
  const int E = in_sizes[1] / 2;
  const size_t nd = (size_t)N * 128;

  // ---- workspace plan (~136 MB; round-2 proved ws >= ~157 MB) ----
  //  Acat [0, N*512)        : [aggm | xb] bf16 N x 256  -> later hid (N x 256)
  //  Bcat [N*512, N*1024)   : [aggs | rnn] bf16 N x 256
  //  xib  [N*1024, N*1280)  : bf16 N x 128 -> later hpre
  //  Wbig 512x256 bf16 (256 KB), bias_big[512] f32, stats[512] f32
  //  CSR: deg[N], off[N+1], cur[N], bucket[E], bsums[512]
  char* base = (char*)d_ws;
  unsigned short* Acat = (unsigned short*)base;
  unsigned short* Bcat = (unsigned short*)(base + (size_t)N * 512);
  unsigned short* xib = (unsigned short*)(base + (size_t)N * 1024);
  unsigned short* hpre = xib;
  unsigned short* hid = Acat;
  unsigned short* Wbig = (unsigned short*)(base + (size_t)N * 1280);
  float* bias_big = (float*)(Wbig + 512 * 256);
  float* stats = bias_big + 512;
  int* deg = (int*)(stats + 512);
  int* off = deg + N;
  int* cur = off + N + 1;
  int* bucket = cur + N;
  int* bsums = bucket + E;
  float* out = (float*)d_out;

  const int ny = (N + 127) / 128;
  const int nblk = (N + 255) / 256;
  const int eblk = (E + 255) / 256;
  dim3 blk(256);

  // prep Wbig/bias_big/stats + CSR build
  prep_k<<<128, blk, 0, stream>>>(W_ih, b_ih, W_hh, b_hh, Wbig, bias_big,
                                  stats);
  init0_k<<<nblk, blk, 0, stream>>>(deg, N);
  hist_k<<<eblk, blk, 0, stream>>>(edges, deg, E);
  scan1_k<<<nblk, blk, 0, stream>>>(deg, off, bsums, N);
  scan2_k<<<1, 512, 0, stream>>>(bsums, nblk);
  scan3_k<<<nblk, blk, 0, stream>>>(off, cur, bsums, N, E);
  fill_k<<<eblk, blk, 0, stream>>>(edges, cur, bucket, E);

  // xb = bf16(x) into Acat[:,128:256]
  cvt_k<<<(int)((nd / 4 + 255) / 256), blk, 0, stream>>>(x, Acat,
                                                         (int)(nd / 4));
  // xib = bf16(xb @ W_aff^T + b_aff)
  mgemm_k<false, false, false><<<dim3(1, ny), blk, 0, stream>>>(
      Acat + 128, 256, W_aff, b_aff, nullptr, xib, nullptr, nullptr, N, 128,
      128);
  // gather: aggm -> Acat left, aggs -> Bcat left
  gather_k<<<(N + 3) / 4, blk, 0, stream>>>(off, bucket, x, xib, Acat, Bcat,
                                            N);
  // fused GRU: gates GEMM + nonlinearity -> rnn into Bcat right
  grurnn_k<<<(N + 31) / 32, blk, 0, stream>>>(Acat, Wbig, bias_big, x, Bcat,
                                              N);
  // hpre = bf16(Bcat @ W_merge^T + b_merge + eps*x)
  mgemm_k<false, false, true><<<dim3(1, ny), blk, 0, stream>>>(
      Bcat, 256, W_merge, b_merge, nullptr, hpre, x, epsp, N, 128, 256);
  // hid = bf16(relu(hpre @ W1^T + b1))  (into Acat region)
  mgemm_k<true, false, false><<<dim3(2, ny), blk, 0, stream>>>(
      hpre, 128, W1, b1, nullptr, hid, nullptr, nullptr, N, 256, 128);
  // out = relu(hid @ W2^T + b2)  (fp32)
  mgemm_k<true, true, false><<<dim3(1, ny), blk, 0, stream>>>(
      hid, 256, W2, b2, out, nullptr, nullptr, nullptr, N, 128, 256);
  // batchnorm
  bn_stats_k<<<512, blk, 0, stream>>>(out, stats, (int)nd);
  bn_final_k<<<1, 128, 0, stream>>>(stats, gamma, beta, N);
  bn_apply_k<<<(int)((nd / 4 + 255) / 256), blk, 0, stream>>>(
      out, stats + 256, stats + 384, (int)(nd / 4));
}

// Round 6
// 777.699 us; speedup vs baseline: 9.7734x; 1.1303x over previous
//
#include <hip/hip_runtime.h>
#include <hip/hip_bf16.h>
#include <math.h>

using bf16 = __hip_bfloat16;
typedef __attribute__((ext_vector_type(8))) short bf16x8;
typedef __attribute__((ext_vector_type(4))) float f32x4;

__device__ __forceinline__ float b2f(unsigned short u) {
  return __uint_as_float(((unsigned)u) << 16);
}
__device__ __forceinline__ unsigned short f2b(float f) {
  bf16 h = __float2bfloat16(f);  // RNE
  return *reinterpret_cast<unsigned short*>(&h);
}
__device__ __forceinline__ ushort4 f2b4(float4 v) {
  return make_ushort4(f2b(v.x), f2b(v.y), f2b(v.z), f2b(v.w));
}

// ---------------------------------------------------------------------------
// MFMA bf16 GEMM (used for xib only): C[N,M] = A[N,K] @ W[M,K]^T + bias.
// A bf16 (row stride lda), W fp32 staged->bf16. bf16 out at row stride ldc.
// ---------------------------------------------------------------------------
__global__ __launch_bounds__(256) void mgemm_k(
    const unsigned short* __restrict__ A, int lda, const float* __restrict__ W,
    const float* __restrict__ bias, unsigned short* __restrict__ Cb, int ldc,
    int N, int M, int K) {
  constexpr int LDA = 72;
  __shared__ unsigned short As[128 * LDA];
  __shared__ unsigned short Ws[128 * LDA];

  const int tid = threadIdx.x;
  const int lane = tid & 63;
  const int wave = tid >> 6;
  const int row0 = blockIdx.y * 128;
  const int m0 = blockIdx.x * 128;
  const int rowhalf = (wave & 1) * 64;
  const int colhalf = (wave >> 1) * 64;
  const int l15 = lane & 15;
  const int quad = lane >> 4;

  f32x4 acc[4][4] = {};

  for (int kc = 0; kc < K; kc += 64) {
#pragma unroll
    for (int i = 0; i < 4; i++) {
      int idx = tid + i * 256;
      int r = idx >> 3;
      int k8 = (idx & 7) * 8;
      int row = row0 + r;
      ushort4 u0 = make_ushort4(0, 0, 0, 0), u1 = u0;
      if (row < N) {
        const unsigned short* s = A + (size_t)row * lda + kc + k8;
        u0 = *(const ushort4*)s;
        u1 = *(const ushort4*)(s + 4);
      }
      *(ushort4*)&As[r * LDA + k8] = u0;
      *(ushort4*)&As[r * LDA + k8 + 4] = u1;
    }
#pragma unroll
    for (int i = 0; i < 8; i++) {
      int idx = tid + i * 256;
      int r = idx >> 4;
      int k4 = idx & 15;
      float4 v = *(const float4*)(W + (size_t)(m0 + r) * K + kc + k4 * 4);
      *(ushort4*)&Ws[r * LDA + k4 * 4] = f2b4(v);
    }
    __syncthreads();
#pragma unroll
    for (int ks = 0; ks < 2; ks++) {
      const int ko = ks * 32 + quad * 8;
      bf16x8 af[4], wf[4];
#pragma unroll
      for (int ri = 0; ri < 4; ri++)
        af[ri] = *(const bf16x8*)&As[(rowhalf + ri * 16 + l15) * LDA + ko];
#pragma unroll
      for (int ci = 0; ci < 4; ci++)
        wf[ci] = *(const bf16x8*)&Ws[(colhalf + ci * 16 + l15) * LDA + ko];
#pragma unroll
      for (int ri = 0; ri < 4; ri++)
#pragma unroll
        for (int ci = 0; ci < 4; ci++)
          acc[ri][ci] = __builtin_amdgcn_mfma_f32_16x16x32_bf16(
              af[ri], wf[ci], acc[ri][ci], 0, 0, 0);
    }
    __syncthreads();
  }
#pragma unroll
  for (int ci = 0; ci < 4; ci++) {
    const int col = m0 + colhalf + ci * 16 + l15;
    const float bv = bias[col];
#pragma unroll
    for (int ri = 0; ri < 4; ri++) {
      const int rbase = row0 + rowhalf + ri * 16 + quad * 4;
#pragma unroll
      for (int r = 0; r < 4; r++) {
        int row = rbase + r;
        if (row >= N) continue;
        Cb[(size_t)row * ldc + col] = f2b(acc[ri][ci][r] + bv);
      }
    }
  }
}

// ---------------------------------------------------------------------------
// Fused GRU: gates = [aggm|xb] @ Wbig^T (bf16 B-frags from L2), LDS gate
// exchange, GRU nonlinearity, rnn -> Bcat[:,128:256]. 32 rows/block.
// ---------------------------------------------------------------------------
__global__ __launch_bounds__(256) void grurnn_k(
    const unsigned short* __restrict__ aggm,
    const unsigned short* __restrict__ xcat,
    const unsigned short* __restrict__ Wbig,
    const float* __restrict__ bias_big, const float* __restrict__ x,
    unsigned short* __restrict__ Bcat, int N) {
  constexpr int LDA = 72;
  constexpr int LDE = 520;
  __shared__ unsigned short As[32 * LDA];
  __shared__ unsigned short Ex[32 * LDE];

  const int tid = threadIdx.x;
  const int lane = tid & 63;
  const int wave = tid >> 6;
  const int l15 = lane & 15;
  const int quad = lane >> 4;
  const int row0 = blockIdx.x * 32;

  f32x4 acc[2][8] = {};

  for (int kc = 0; kc < 256; kc += 64) {
    {
      int r = tid >> 3;
      int k8 = (tid & 7) * 8;
      int row = row0 + r;
      ushort4 u0 = make_ushort4(0, 0, 0, 0), u1 = u0;
      if (row < N) {
        const unsigned short* s =
            (kc < 128) ? aggm + (size_t)row * 128 + kc + k8
                       : xcat + (size_t)row * 256 + (kc - 128) + k8;
        u0 = *(const ushort4*)s;
        u1 = *(const ushort4*)(s + 4);
      }
      *(ushort4*)&As[r * LDA + k8] = u0;
      *(ushort4*)&As[r * LDA + k8 + 4] = u1;
    }
    __syncthreads();
#pragma unroll
    for (int ks = 0; ks < 2; ks++) {
      const int ko = ks * 32 + quad * 8;
      bf16x8 af[2];
#pragma unroll
      for (int ri = 0; ri < 2; ri++)
        af[ri] = *(const bf16x8*)&As[(ri * 16 + l15) * LDA + ko];
#pragma unroll
      for (int ci = 0; ci < 8; ci++) {
        int m = wave * 128 + ci * 16 + l15;
        bf16x8 wf = *(const bf16x8*)&Wbig[(size_t)m * 256 + kc + ko];
#pragma unroll
        for (int ri = 0; ri < 2; ri++)
          acc[ri][ci] = __builtin_amdgcn_mfma_f32_16x16x32_bf16(
              af[ri], wf, acc[ri][ci], 0, 0, 0);
      }
    }
    __syncthreads();
  }
#pragma unroll
  for (int ci = 0; ci < 8; ci++) {
    const int col = wave * 128 + ci * 16 + l15;
#pragma unroll
    for (int ri = 0; ri < 2; ri++) {
      const int rb = ri * 16 + quad * 4;
#pragma unroll
      for (int r = 0; r < 4; r++) Ex[(rb + r) * LDE + col] = f2b(acc[ri][ci][r]);
    }
  }
  __syncthreads();
#pragma unroll
  for (int it = 0; it < 8; it++) {
    int idx = tid + it * 256;
    int r = idx >> 6;
    int f = (idx & 63) * 2;
    int row = row0 + r;
    if (row >= N) continue;
    ushort2 usr = *(ushort2*)&Ex[r * LDE + f];
    ushort2 usz = *(ushort2*)&Ex[r * LDE + 128 + f];
    ushort2 usi = *(ushort2*)&Ex[r * LDE + 256 + f];
    ushort2 ush = *(ushort2*)&Ex[r * LDE + 384 + f];
    float2 br = *(const float2*)&bias_big[f];
    float2 bz = *(const float2*)&bias_big[128 + f];
    float2 bi = *(const float2*)&bias_big[256 + f];
    float2 bh = *(const float2*)&bias_big[384 + f];
    float2 xv = *(const float2*)&x[(size_t)row * 128 + f];
    float rg0 = 1.f / (1.f + __expf(-(b2f(usr.x) + br.x)));
    float rg1 = 1.f / (1.f + __expf(-(b2f(usr.y) + br.y)));
    float zg0 = 1.f / (1.f + __expf(-(b2f(usz.x) + bz.x)));
    float zg1 = 1.f / (1.f + __expf(-(b2f(usz.y) + bz.y)));
    float nc0 = tanhf(b2f(usi.x) + bi.x + rg0 * (b2f(ush.x) + bh.x));
    float nc1 = tanhf(b2f(usi.y) + bi.y + rg1 * (b2f(ush.y) + bh.y));
    float o0 = (1.f - zg0) * nc0 + zg0 * xv.x;
    float o1 = (1.f - zg1) * nc1 + zg1 * xv.y;
    *(ushort2*)&Bcat[(size_t)row * 256 + 128 + f] =
        make_ushort2(f2b(o0), f2b(o1));
  }
}

// ---------------------------------------------------------------------------
// Fused backbone: per 64-row tile: hpre = Bcat@Wm^T+bm+ep*xb (LDS), hid =
// relu(hpre@W1^T+b1) (LDS), out = relu(hid@W2^T+b2) -> global + BN partial
// stats. Weights pre-converted bf16, streamed from L2 (no staging/sync).
// ---------------------------------------------------------------------------
__global__ __launch_bounds__(256) void backbone_k(
    const unsigned short* __restrict__ Bcat,
    const unsigned short* __restrict__ xcat,
    const unsigned short* __restrict__ Wmb, const float* __restrict__ bm,
    const unsigned short* __restrict__ W1b, const float* __restrict__ b1,
    const unsigned short* __restrict__ W2b, const float* __restrict__ b2,
    const float* __restrict__ epsp, float* __restrict__ out,
    float* __restrict__ stats, int N) {
  constexpr int LDH = 136;   // 128 + 8 (16B-aligned b128, 2-way banks: free)
  constexpr int LDH2 = 264;  // 256 + 8
  __shared__ unsigned short Hp[64 * LDH];
  __shared__ unsigned short Hd[64 * LDH2];
  __shared__ float sbn[128], qbn[128];

  const int tid = threadIdx.x;
  const int lane = tid & 63;
  const int wave = tid >> 6;
  const int l15 = lane & 15;
  const int quad = lane >> 4;
  const int row0 = blockIdx.x * 64;
  if (tid < 128) {
    sbn[tid] = 0.f;
    qbn[tid] = 0.f;
  }
  const float ep = epsp[0];

  // ---- phase 1: merge (K=256, M=128), out cols wave*32..+32 ----
  {
    f32x4 acc[4][2] = {};
#pragma unroll
    for (int ks = 0; ks < 8; ks++) {
      const int ko = ks * 32 + quad * 8;
      bf16x8 af[4];
#pragma unroll
      for (int ri = 0; ri < 4; ri++)
        af[ri] =
            *(const bf16x8*)&Bcat[(size_t)(row0 + ri * 16 + l15) * 256 + ko];
#pragma unroll
      for (int ci = 0; ci < 2; ci++) {
        bf16x8 wf =
            *(const bf16x8*)&Wmb[(size_t)(wave * 32 + ci * 16 + l15) * 256 + ko];
#pragma unroll
        for (int ri = 0; ri < 4; ri++)
          acc[ri][ci] = __builtin_amdgcn_mfma_f32_16x16x32_bf16(
              af[ri], wf, acc[ri][ci], 0, 0, 0);
      }
    }
#pragma unroll
    for (int ci = 0; ci < 2; ci++) {
      int c = wave * 32 + ci * 16 + l15;
      float bv = bm[c];
#pragma unroll
      for (int ri = 0; ri < 4; ri++) {
#pragma unroll
        for (int r = 0; r < 4; r++) {
          int lr = ri * 16 + quad * 4 + r;
          int row = row0 + lr;
          float v = acc[ri][ci][r] + bv;
          if (row < N) v += ep * b2f(xcat[(size_t)row * 256 + c]);
          Hp[lr * LDH + c] = f2b(v);
        }
      }
    }
  }
  __syncthreads();
  // ---- phase 2: W1 (K=128, M=256), out cols wave*64..+64 ----
  {
    f32x4 acc[4][4] = {};
#pragma unroll
    for (int ks = 0; ks < 4; ks++) {
      const int ko = ks * 32 + quad * 8;
      bf16x8 af[4];
#pragma unroll
      for (int ri = 0; ri < 4; ri++)
        af[ri] = *(const bf16x8*)&Hp[(ri * 16 + l15) * LDH + ko];
#pragma unroll
      for (int ci = 0; ci < 4; ci++) {
        bf16x8 wf =
            *(const bf16x8*)&W1b[(size_t)(wave * 64 + ci * 16 + l15) * 128 + ko];
#pragma unroll
        for (int ri = 0; ri < 4; ri++)
          acc[ri][ci] = __builtin_amdgcn_mfma_f32_16x16x32_bf16(
              af[ri], wf, acc[ri][ci], 0, 0, 0);
      }
    }
    __syncthreads();  // Hp reads done before Hd writes (regions distinct; sync
                      // orders phases for all waves)
#pragma unroll
    for (int ci = 0; ci < 4; ci++) {
      int c = wave * 64 + ci * 16 + l15;
      float bv = b1[c];
#pragma unroll
      for (int ri = 0; ri < 4; ri++) {
#pragma unroll
        for (int r = 0; r < 4; r++) {
          int lr = ri * 16 + quad * 4 + r;
          Hd[lr * LDH2 + c] = f2b(fmaxf(acc[ri][ci][r] + bv, 0.f));
        }
      }
    }
  }
  __syncthreads();
  // ---- phase 3: W2 (K=256, M=128), out cols wave*32..+32 + BN stats ----
  {
    f32x4 acc[4][2] = {};
#pragma unroll
    for (int ks = 0; ks < 8; ks++) {
      const int ko = ks * 32 + quad * 8;
      bf16x8 af[4];
#pragma unroll
      for (int ri = 0; ri < 4; ri++)
        af[ri] = *(const bf16x8*)&Hd[(ri * 16 + l15) * LDH2 + ko];
#pragma unroll
      for (int ci = 0; ci < 2; ci++) {
        bf16x8 wf =
            *(const bf16x8*)&W2b[(size_t)(wave * 32 + ci * 16 + l15) * 256 + ko];
#pragma unroll
        for (int ri = 0; ri < 4; ri++)
          acc[ri][ci] = __builtin_amdgcn_mfma_f32_16x16x32_bf16(
              af[ri], wf, acc[ri][ci], 0, 0, 0);
      }
    }
#pragma unroll
    for (int ci = 0; ci < 2; ci++) {
      int c = wave * 32 + ci * 16 + l15;
      float bv = b2[c];
      float s = 0.f, q = 0.f;
#pragma unroll
      for (int ri = 0; ri < 4; ri++) {
#pragma unroll
        for (int r = 0; r < 4; r++) {
          int lr = ri * 16 + quad * 4 + r;
          int row = row0 + lr;
          if (row >= N) continue;
          float v = fmaxf(acc[ri][ci][r] + bv, 0.f);
          out[(size_t)row * 128 + c] = v;
          s += v;
          q += v * v;
        }
      }
      atomicAdd(&sbn[c], s);
      atomicAdd(&qbn[c], q);
    }
  }
  __syncthreads();
  if (tid < 128) {
    atomicAdd(&stats[tid], sbn[tid]);
    atomicAdd(&stats[128 + tid], qbn[tid]);
  }
}

// ---------------------------------------------------------------------------
// prep: Wbig (512x256 gate matrix), Wmb/W1b/W2b bf16 copies, bias_big,
// zero stats + deg.
// ---------------------------------------------------------------------------
__global__ __launch_bounds__(256) void prep_k(
    const float* __restrict__ W_ih, const float* __restrict__ b_ih,
    const float* __restrict__ W_hh, const float* __restrict__ b_hh,
    const float* __restrict__ Wm, const float* __restrict__ W1,
    const float* __restrict__ W2, unsigned short* __restrict__ Wbig,
    unsigned short* __restrict__ Wmb, unsigned short* __restrict__ W1b,
    unsigned short* __restrict__ W2b, float* __restrict__ bias_big,
    float* __restrict__ stats, int* __restrict__ deg, int N) {
  int idx = blockIdx.x * 256 + threadIdx.x;
  if (idx < N) deg[idx] = 0;
  if (idx < 32768) {  // Wbig
    int m = idx >> 6;
    int k4 = (idx & 63) * 4;
    const float* src = nullptr;
    int koff = 0;
    if (m < 256) {
      if (k4 < 128) { src = W_ih + (size_t)m * 128; koff = k4; }
      else          { src = W_hh + (size_t)m * 128; koff = k4 - 128; }
    } else if (m < 384) {
      if (k4 < 128) { src = W_ih + (size_t)m * 128; koff = k4; }
    } else {
      if (k4 >= 128) { src = W_hh + (size_t)(m - 128) * 128; koff = k4 - 128; }
    }
    ushort4 o = make_ushort4(0, 0, 0, 0);
    if (src) o = f2b4(*(const float4*)(src + koff));
    *(ushort4*)&Wbig[(size_t)m * 256 + k4] = o;
  }
  if (idx < 8192) {
    int m = idx >> 6;
    int k4 = (idx & 63) * 4;  // 128x256 shapes
    *(ushort4*)&Wmb[(size_t)m * 256 + k4] =
        f2b4(*(const float4*)(Wm + (size_t)m * 256 + k4));
    *(ushort4*)&W2b[(size_t)m * 256 + k4] =
        f2b4(*(const float4*)(W2 + (size_t)m * 256 + k4));
    int m2 = idx >> 5;
    int k42 = (idx & 31) * 4;  // 256x128
    *(ushort4*)&W1b[(size_t)m2 * 128 + k42] =
        f2b4(*(const float4*)(W1 + (size_t)m2 * 128 + k42));
  }
  if (blockIdx.x == 0) {
    int t = threadIdx.x;
    stats[t] = 0.f;
    stats[256 + t] = 0.f;
#pragma unroll
    for (int h = 0; h < 2; h++) {
      int mm = t + h * 256;
      float b;
      if (mm < 256) b = b_ih[mm] + b_hh[mm];
      else if (mm < 384) b = b_ih[mm];
      else b = b_hh[mm - 128];
      bias_big[mm] = b;
    }
  }
}

// ---------------------------------------------------------------------------
// CSR build
// ---------------------------------------------------------------------------
__global__ __launch_bounds__(256) void hist_k(const int* __restrict__ edges,
                                              int* __restrict__ deg, int E) {
  int e = blockIdx.x * 256 + threadIdx.x;
  if (e < E) atomicAdd(&deg[edges[(size_t)E + e]], 1);
}

__global__ __launch_bounds__(256) void scan1_k(const int* __restrict__ deg,
                                               int* __restrict__ off,
                                               int* __restrict__ bsums, int N) {
  __shared__ int s[256];
  int t = threadIdx.x;
  int i = blockIdx.x * 256 + t;
  int v = (i < N) ? deg[i] : 0;
  s[t] = v;
  __syncthreads();
#pragma unroll
  for (int d = 1; d < 256; d <<= 1) {
    int u = (t >= d) ? s[t - d] : 0;
    __syncthreads();
    s[t] += u;
    __syncthreads();
  }
  if (i < N) off[i] = s[t] - v;
  if (t == 255) bsums[blockIdx.x] = s[255];
}

__global__ __launch_bounds__(512) void scan2_k(int* __restrict__ bsums,
                                               int nb) {
  __shared__ int s[512];
  int t = threadIdx.x;
  int v = (t < nb) ? bsums[t] : 0;
  s[t] = v;
  __syncthreads();
#pragma unroll
  for (int d = 1; d < 512; d <<= 1) {
    int u = (t >= d) ? s[t - d] : 0;
    __syncthreads();
    s[t] += u;
    __syncthreads();
  }
  if (t < nb) bsums[t] = s[t] - v;
}

__global__ __launch_bounds__(256) void scan3_k(int* __restrict__ off,
                                               int* __restrict__ cur,
                                               const int* __restrict__ bsums,
                                               int N, int E) {
  int i = blockIdx.x * 256 + threadIdx.x;
  if (i < N) {
    int o = off[i] + bsums[blockIdx.x];
    off[i] = o;
    cur[i] = o;
  }
  if (i == 0) off[N] = E;
}

__global__ __launch_bounds__(256) void fill_k(const int* __restrict__ edges,
                                              int* __restrict__ cur,
                                              int* __restrict__ bucket, int E) {
  int e = blockIdx.x * 256 + threadIdx.x;
  if (e >= E) return;
  int src = edges[e];
  int dst = edges[(size_t)E + e];
  int pos = atomicAdd(&cur[dst], 1);
  bucket[pos] = src;
}

// ---------------------------------------------------------------------------
// cvt: xb = bf16(x) into xcat left half (row stride 256)
// ---------------------------------------------------------------------------
__global__ __launch_bounds__(256) void cvt_k(const float* __restrict__ x,
                                             unsigned short* __restrict__ xcat,
                                             int ngroups) {
  int g = blockIdx.x * 256 + threadIdx.x;
  if (g >= ngroups) return;
  int n = g >> 5;
  int j = (g & 31) * 4;
  float4 v = *(const float4*)&x[(size_t)n * 128 + j];
  *(ushort4*)&xcat[(size_t)n * 256 + j] = f2b4(v);
}

// ---------------------------------------------------------------------------
// gather-reduce over packed xcat=[xb|xib]: one wave/node, 2 features/lane,
// depth-2 index prefetch. aggm dense N x 128; aggs -> Bcat left half.
// ---------------------------------------------------------------------------
__global__ __launch_bounds__(256) void gather_k(
    const int* __restrict__ off, const int* __restrict__ bucket,
    const unsigned short* __restrict__ xcat, unsigned short* __restrict__ aggm,
    unsigned short* __restrict__ Bcat, int N) {
  int node = blockIdx.x * 4 + (threadIdx.x >> 6);
  if (node >= N) return;
  int f = (threadIdx.x & 63) * 2;
  int j0 = off[node], jend = off[node + 1];
  float s0 = 0.f, s1 = 0.f, m0 = -INFINITY, m1 = -INFINITY;
  int p0 = (j0 < jend) ? bucket[j0] : 0;
  int p1 = (j0 + 1 < jend) ? bucket[j0 + 1] : 0;
  for (int j = j0; j < jend; j++) {
    int src = p0;
    p0 = p1;
    p1 = (j + 2 < jend) ? bucket[j + 2] : 0;
    ushort2 xv = *(const ushort2*)(xcat + (size_t)src * 256 + f);
    ushort2 uv = *(const ushort2*)(xcat + (size_t)src * 256 + 128 + f);
    s0 += b2f(xv.x);
    s1 += b2f(xv.y);
    m0 = fmaxf(m0, b2f(uv.x));
    m1 = fmaxf(m1, b2f(uv.y));
  }
  bool nz = jend > j0;
  *(ushort2*)&aggm[(size_t)node * 128 + f] =
      make_ushort2(nz ? f2b(m0) : (unsigned short)0,
                   nz ? f2b(m1) : (unsigned short)0);
  *(ushort2*)&Bcat[(size_t)node * 256 + f] = make_ushort2(f2b(s0), f2b(s1));
}

// ---------------------------------------------------------------------------
// BatchNorm finalize + apply
// ---------------------------------------------------------------------------
__global__ void bn_final_k(float* __restrict__ stats,
                           const float* __restrict__ gamma,
                           const float* __restrict__ beta, int N) {
  int d = threadIdx.x;
  if (d >= 128) return;
  float invn = 1.f / (float)N;
  float mean = stats[d] * invn;
  float var = stats[128 + d] * invn - mean * mean;
  var = fmaxf(var, 0.f);
  float sc = gamma[d] * rsqrtf(var + 1e-5f);
  stats[256 + d] = sc;
  stats[384 + d] = beta[d] - mean * sc;
}

__global__ __launch_bounds__(256) void bn_apply_k(float* __restrict__ out,
                                                  const float* __restrict__ sc,
                                                  const float* __restrict__ sh,
                                                  int nd4) {
  int g = blockIdx.x * 256 + threadIdx.x;
  if (g >= nd4) return;
  float4 v = ((float4*)out)[g];
  int d = (g & 31) * 4;
  v.x = v.x * sc[d + 0] + sh[d + 0];
  v.y = v.y * sc[d + 1] + sh[d + 1];
  v.z = v.z * sc[d + 2] + sh[d + 2];
  v.w = v.w * sc[d + 3] + sh[d + 3];
  ((float4*)out)[g] = v;
}

// ---------------------------------------------------------------------------
extern "C" void kernel_launch(void* const* d_in, const int* in_sizes, int n_in,
                              void* d_out, int out_size, void* d_ws,
                              size_t ws_size, hipStream_t stream) {
  (void)n_in;
  (void)out_size;
  (void)ws_size;
  const float* x = (const float*)d_in[0];
  const int* edges = (const int*)d_in[1];
  const float* W_aff = (const float*)d_in[2];
  const float* b_aff = (const float*)d_in[3];
  const float* W_ih = (const float*)d_in[4];
  const float* b_ih = (const float*)d_in[5];
  const float* W_hh = (const float*)d_in[6];
  const float* b_hh = (const float*)d_in[7];
  const float* W_merge = (const float*)d_in[8];
  const float* b_merge = (const float*)d_in[9];
  const float* epsp = (const float*)d_in[10];
  const float* W1 = (const float*)d_in[11];
  const float* b1 = (const float*)d_in[12];
  const float* W2 = (const float*)d_in[13];
  const float* b2 = (const float*)d_in[14];
  const float* gamma = (const float*)d_in[15];
  const float* beta = (const float*)d_in[16];

  const int N = in_sizes[0] / 128;
  const int E = in_sizes[1] / 2;
  const size_t nd = (size_t)N * 128;

  // ---- workspace (~136 MB) ----
  //  xcat [0, N*512)        : [xb | xib] bf16 N x 256
  //  Bcat [N*512, N*1024)   : [aggs | rnn] bf16 N x 256
  //  aggm [N*1024, N*1280)  : bf16 N x 128
  //  Wbig(512x256) Wmb(128x256) W1b(256x128) W2b(128x256) bf16
  //  bias_big[512], stats[512] f32; CSR: deg, off, cur, bucket, bsums
  char* base = (char*)d_ws;
  unsigned short* xcat = (unsigned short*)base;
  unsigned short* Bcat = (unsigned short*)(base + (size_t)N * 512);
  unsigned short* aggm = (unsigned short*)(base + (size_t)N * 1024);
  unsigned short* Wbig = (unsigned short*)(base + (size_t)N * 1280);
  unsigned short* Wmb = Wbig + 512 * 256;
  unsigned short* W1b = Wmb + 128 * 256;
  unsigned short* W2b = W1b + 256 * 128;
  float* bias_big = (float*)(W2b + 128 * 256);
  float* stats = bias_big + 512;
  int* deg = (int*)(stats + 512);
  int* off = deg + N;
  int* cur = off + N + 1;
  int* bucket = cur + N;
  int* bsums = bucket + E;
  float* out = (float*)d_out;

  const int ny = (N + 127) / 128;
  const int nblk = (N + 255) / 256;
  const int eblk = (E + 255) / 256;
  const int pgrid = nblk > 128 ? nblk : 128;
  dim3 blk(256);

  prep_k<<<pgrid, blk, 0, stream>>>(W_ih, b_ih, W_hh, b_hh, W_merge, W1, W2,
                                    Wbig, Wmb, W1b, W2b, bias_big, stats, deg,
                                    N);
  hist_k<<<eblk, blk, 0, stream>>>(edges, deg, E);
  scan1_k<<<nblk, blk, 0, stream>>>(deg, off, bsums, N);
  scan2_k<<<1, 512, 0, stream>>>(bsums, nblk);
  scan3_k<<<nblk, blk, 0, stream>>>(off, cur, bsums, N, E);
  fill_k<<<eblk, blk, 0, stream>>>(edges, cur, bucket, E);

  cvt_k<<<(int)((nd / 4 + 255) / 256), blk, 0, stream>>>(x, xcat,
                                                         (int)(nd / 4));
  // xib = bf16(xb @ W_aff^T + b_aff) into xcat right half
  mgemm_k<<<dim3(1, ny), blk, 0, stream>>>(xcat, 256, W_aff, b_aff, xcat + 128,
                                           256, N, 128, 128);
  gather_k<<<(N + 3) / 4, blk, 0, stream>>>(off, bucket, xcat, aggm, Bcat, N);
  grurnn_k<<<(N + 31) / 32, blk, 0, stream>>>(aggm, xcat, Wbig, bias_big, x,
                                              Bcat, N);
  backbone_k<<<(N + 63) / 64, blk, 0, stream>>>(Bcat, xcat, Wmb, b_merge, W1b,
                                                b1, W2b, b2, epsp, out, stats,
                                                N);
  bn_final_k<<<1, 128, 0, stream>>>(stats, gamma, beta, N);
  bn_apply_k<<<(int)((nd / 4 + 255) / 256), blk, 0, stream>>>(
      out, stats + 256, stats + 384, (int)(nd / 4));
}

// Round 7
// 738.196 us; speedup vs baseline: 10.2964x; 1.0535x over previous
//
#include <hip/hip_runtime.h>
#include <hip/hip_bf16.h>
#include <math.h>

using bf16 = __hip_bfloat16;
typedef __attribute__((ext_vector_type(8))) short bf16x8;
typedef __attribute__((ext_vector_type(4))) float f32x4;

__device__ __forceinline__ float b2f(unsigned short u) {
  return __uint_as_float(((unsigned)u) << 16);
}
__device__ __forceinline__ unsigned short f2b(float f) {
  bf16 h = __float2bfloat16(f);  // RNE
  return *reinterpret_cast<unsigned short*>(&h);
}
__device__ __forceinline__ ushort4 f2b4(float4 v) {
  return make_ushort4(f2b(v.x), f2b(v.y), f2b(v.z), f2b(v.w));
}

// ---------------------------------------------------------------------------
// MFMA bf16 GEMM (xib only): C[N,M] = A[N,K] @ W[M,K]^T + bias.
// ---------------------------------------------------------------------------
__global__ __launch_bounds__(256) void mgemm_k(
    const unsigned short* __restrict__ A, int lda, const float* __restrict__ W,
    const float* __restrict__ bias, unsigned short* __restrict__ Cb, int ldc,
    int N, int M, int K) {
  constexpr int LDA = 72;
  __shared__ unsigned short As[128 * LDA];
  __shared__ unsigned short Ws[128 * LDA];

  const int tid = threadIdx.x;
  const int lane = tid & 63;
  const int wave = tid >> 6;
  const int row0 = blockIdx.y * 128;
  const int m0 = blockIdx.x * 128;
  const int rowhalf = (wave & 1) * 64;
  const int colhalf = (wave >> 1) * 64;
  const int l15 = lane & 15;
  const int quad = lane >> 4;

  f32x4 acc[4][4] = {};

  for (int kc = 0; kc < K; kc += 64) {
#pragma unroll
    for (int i = 0; i < 4; i++) {
      int idx = tid + i * 256;
      int r = idx >> 3;
      int k8 = (idx & 7) * 8;
      int row = row0 + r;
      ushort4 u0 = make_ushort4(0, 0, 0, 0), u1 = u0;
      if (row < N) {
        const unsigned short* s = A + (size_t)row * lda + kc + k8;
        u0 = *(const ushort4*)s;
        u1 = *(const ushort4*)(s + 4);
      }
      *(ushort4*)&As[r * LDA + k8] = u0;
      *(ushort4*)&As[r * LDA + k8 + 4] = u1;
    }
#pragma unroll
    for (int i = 0; i < 8; i++) {
      int idx = tid + i * 256;
      int r = idx >> 4;
      int k4 = idx & 15;
      float4 v = *(const float4*)(W + (size_t)(m0 + r) * K + kc + k4 * 4);
      *(ushort4*)&Ws[r * LDA + k4 * 4] = f2b4(v);
    }
    __syncthreads();
#pragma unroll
    for (int ks = 0; ks < 2; ks++) {
      const int ko = ks * 32 + quad * 8;
      bf16x8 af[4], wf[4];
#pragma unroll
      for (int ri = 0; ri < 4; ri++)
        af[ri] = *(const bf16x8*)&As[(rowhalf + ri * 16 + l15) * LDA + ko];
#pragma unroll
      for (int ci = 0; ci < 4; ci++)
        wf[ci] = *(const bf16x8*)&Ws[(colhalf + ci * 16 + l15) * LDA + ko];
#pragma unroll
      for (int ri = 0; ri < 4; ri++)
#pragma unroll
        for (int ci = 0; ci < 4; ci++)
          acc[ri][ci] = __builtin_amdgcn_mfma_f32_16x16x32_bf16(
              af[ri], wf[ci], acc[ri][ci], 0, 0, 0);
    }
    __syncthreads();
  }
#pragma unroll
  for (int ci = 0; ci < 4; ci++) {
    const int col = m0 + colhalf + ci * 16 + l15;
    const float bv = bias[col];
#pragma unroll
    for (int ri = 0; ri < 4; ri++) {
      const int rbase = row0 + rowhalf + ri * 16 + quad * 4;
#pragma unroll
      for (int r = 0; r < 4; r++) {
        int row = rbase + r;
        if (row >= N) continue;
        Cb[(size_t)row * ldc + col] = f2b(acc[ri][ci][r] + bv);
      }
    }
  }
}

// ---------------------------------------------------------------------------
// Fused GRU with PERMUTED Wbig: each lane's 8 output cols are the 4 gates x
// 2 features it needs -> GRU entirely in registers (no LDS gate exchange).
// Gate col mapping: c = wave*128 + (g + 4*fi)*16 + l15, f = wave*32+fi*16+l15.
// ---------------------------------------------------------------------------
__global__ __launch_bounds__(256) void grurnn_k(
    const unsigned short* __restrict__ aggm,
    const unsigned short* __restrict__ xcat,
    const unsigned short* __restrict__ Wbig,
    const float* __restrict__ bias_big, unsigned short* __restrict__ Bcat,
    int N) {
  constexpr int LDA = 72;
  __shared__ unsigned short As[32 * LDA];

  const int tid = threadIdx.x;
  const int lane = tid & 63;
  const int wave = tid >> 6;
  const int l15 = lane & 15;
  const int quad = lane >> 4;
  const int row0 = blockIdx.x * 32;

  f32x4 acc[2][8] = {};

  for (int kc = 0; kc < 256; kc += 64) {
    {
      int r = tid >> 3;
      int k8 = (tid & 7) * 8;
      int row = row0 + r;
      ushort4 u0 = make_ushort4(0, 0, 0, 0), u1 = u0;
      if (row < N) {
        const unsigned short* s =
            (kc < 128) ? aggm + (size_t)row * 128 + kc + k8
                       : xcat + (size_t)row * 256 + (kc - 128) + k8;
        u0 = *(const ushort4*)s;
        u1 = *(const ushort4*)(s + 4);
      }
      *(ushort4*)&As[r * LDA + k8] = u0;
      *(ushort4*)&As[r * LDA + k8 + 4] = u1;
    }
    __syncthreads();
#pragma unroll
    for (int ks = 0; ks < 2; ks++) {
      const int ko = ks * 32 + quad * 8;
      bf16x8 af[2];
#pragma unroll
      for (int ri = 0; ri < 2; ri++)
        af[ri] = *(const bf16x8*)&As[(ri * 16 + l15) * LDA + ko];
#pragma unroll
      for (int ci = 0; ci < 8; ci++) {
        int m = wave * 128 + ci * 16 + l15;
        bf16x8 wf = *(const bf16x8*)&Wbig[(size_t)m * 256 + kc + ko];
#pragma unroll
        for (int ri = 0; ri < 2; ri++)
          acc[ri][ci] = __builtin_amdgcn_mfma_f32_16x16x32_bf16(
              af[ri], wf, acc[ri][ci], 0, 0, 0);
      }
    }
    __syncthreads();
  }
  // register GRU: acc[ri][4*fi+g][r] = gate g of feature f, row quad*4+r+16ri
#pragma unroll
  for (int fi = 0; fi < 2; fi++) {
    const int f = wave * 32 + fi * 16 + l15;
    const float br = bias_big[f];
    const float bz = bias_big[128 + f];
    const float bi = bias_big[256 + f];
    const float bh = bias_big[384 + f];
#pragma unroll
    for (int ri = 0; ri < 2; ri++) {
#pragma unroll
      for (int r = 0; r < 4; r++) {
        int row = row0 + ri * 16 + quad * 4 + r;
        if (row >= N) continue;
        float rg = 1.f / (1.f + __expf(-(acc[ri][4 * fi + 0][r] + br)));
        float zg = 1.f / (1.f + __expf(-(acc[ri][4 * fi + 1][r] + bz)));
        float nc =
            tanhf(acc[ri][4 * fi + 2][r] + bi + rg * (acc[ri][4 * fi + 3][r] + bh));
        float xv = b2f(xcat[(size_t)row * 256 + f]);
        Bcat[(size_t)row * 256 + 128 + f] = f2b((1.f - zg) * nc + zg * xv);
      }
    }
  }
}

// ---------------------------------------------------------------------------
// Fused backbone: merge(+eps*xb) -> W1/relu -> W2/relu -> out + BN partials.
// ---------------------------------------------------------------------------
__global__ __launch_bounds__(256) void backbone_k(
    const unsigned short* __restrict__ Bcat,
    const unsigned short* __restrict__ xcat,
    const unsigned short* __restrict__ Wmb, const float* __restrict__ bm,
    const unsigned short* __restrict__ W1b, const float* __restrict__ b1,
    const unsigned short* __restrict__ W2b, const float* __restrict__ b2,
    const float* __restrict__ epsp, float* __restrict__ out,
    float* __restrict__ stats, int N) {
  constexpr int LDH = 136;
  constexpr int LDH2 = 264;
  __shared__ unsigned short Hp[64 * LDH];
  __shared__ unsigned short Hd[64 * LDH2];
  __shared__ float sbn[128], qbn[128];

  const int tid = threadIdx.x;
  const int lane = tid & 63;
  const int wave = tid >> 6;
  const int l15 = lane & 15;
  const int quad = lane >> 4;
  const int row0 = blockIdx.x * 64;
  if (tid < 128) {
    sbn[tid] = 0.f;
    qbn[tid] = 0.f;
  }
  const float ep = epsp[0];

  {  // phase 1: merge (K=256, M=128)
    f32x4 acc[4][2] = {};
#pragma unroll
    for (int ks = 0; ks < 8; ks++) {
      const int ko = ks * 32 + quad * 8;
      bf16x8 af[4];
#pragma unroll
      for (int ri = 0; ri < 4; ri++)
        af[ri] =
            *(const bf16x8*)&Bcat[(size_t)(row0 + ri * 16 + l15) * 256 + ko];
#pragma unroll
      for (int ci = 0; ci < 2; ci++) {
        bf16x8 wf =
            *(const bf16x8*)&Wmb[(size_t)(wave * 32 + ci * 16 + l15) * 256 + ko];
#pragma unroll
        for (int ri = 0; ri < 4; ri++)
          acc[ri][ci] = __builtin_amdgcn_mfma_f32_16x16x32_bf16(
              af[ri], wf, acc[ri][ci], 0, 0, 0);
      }
    }
#pragma unroll
    for (int ci = 0; ci < 2; ci++) {
      int c = wave * 32 + ci * 16 + l15;
      float bv = bm[c];
#pragma unroll
      for (int ri = 0; ri < 4; ri++) {
#pragma unroll
        for (int r = 0; r < 4; r++) {
          int lr = ri * 16 + quad * 4 + r;
          int row = row0 + lr;
          float v = acc[ri][ci][r] + bv;
          if (row < N) v += ep * b2f(xcat[(size_t)row * 256 + c]);
          Hp[lr * LDH + c] = f2b(v);
        }
      }
    }
  }
  __syncthreads();
  {  // phase 2: W1 (K=128, M=256)
    f32x4 acc[4][4] = {};
#pragma unroll
    for (int ks = 0; ks < 4; ks++) {
      const int ko = ks * 32 + quad * 8;
      bf16x8 af[4];
#pragma unroll
      for (int ri = 0; ri < 4; ri++)
        af[ri] = *(const bf16x8*)&Hp[(ri * 16 + l15) * LDH + ko];
#pragma unroll
      for (int ci = 0; ci < 4; ci++) {
        bf16x8 wf =
            *(const bf16x8*)&W1b[(size_t)(wave * 64 + ci * 16 + l15) * 128 + ko];
#pragma unroll
        for (int ri = 0; ri < 4; ri++)
          acc[ri][ci] = __builtin_amdgcn_mfma_f32_16x16x32_bf16(
              af[ri], wf, acc[ri][ci], 0, 0, 0);
      }
    }
    __syncthreads();
#pragma unroll
    for (int ci = 0; ci < 4; ci++) {
      int c = wave * 64 + ci * 16 + l15;
      float bv = b1[c];
#pragma unroll
      for (int ri = 0; ri < 4; ri++) {
#pragma unroll
        for (int r = 0; r < 4; r++) {
          int lr = ri * 16 + quad * 4 + r;
          Hd[lr * LDH2 + c] = f2b(fmaxf(acc[ri][ci][r] + bv, 0.f));
        }
      }
    }
  }
  __syncthreads();
  {  // phase 3: W2 (K=256, M=128) + BN partials
    f32x4 acc[4][2] = {};
#pragma unroll
    for (int ks = 0; ks < 8; ks++) {
      const int ko = ks * 32 + quad * 8;
      bf16x8 af[4];
#pragma unroll
      for (int ri = 0; ri < 4; ri++)
        af[ri] = *(const bf16x8*)&Hd[(ri * 16 + l15) * LDH2 + ko];
#pragma unroll
      for (int ci = 0; ci < 2; ci++) {
        bf16x8 wf =
            *(const bf16x8*)&W2b[(size_t)(wave * 32 + ci * 16 + l15) * 256 + ko];
#pragma unroll
        for (int ri = 0; ri < 4; ri++)
          acc[ri][ci] = __builtin_amdgcn_mfma_f32_16x16x32_bf16(
              af[ri], wf, acc[ri][ci], 0, 0, 0);
      }
    }
#pragma unroll
    for (int ci = 0; ci < 2; ci++) {
      int c = wave * 32 + ci * 16 + l15;
      float bv = b2[c];
      float s = 0.f, q = 0.f;
#pragma unroll
      for (int ri = 0; ri < 4; ri++) {
#pragma unroll
        for (int r = 0; r < 4; r++) {
          int lr = ri * 16 + quad * 4 + r;
          int row = row0 + lr;
          if (row >= N) continue;
          float v = fmaxf(acc[ri][ci][r] + bv, 0.f);
          out[(size_t)row * 128 + c] = v;
          s += v;
          q += v * v;
        }
      }
      atomicAdd(&sbn[c], s);
      atomicAdd(&qbn[c], q);
    }
  }
  __syncthreads();
  if (tid < 128) {
    atomicAdd(&stats[tid], sbn[tid]);
    atomicAdd(&stats[128 + tid], qbn[tid]);
  }
}

// ---------------------------------------------------------------------------
// prep: permuted Wbig, Wmb/W1b/W2b bf16 copies, bias_big, zero stats + deg.
// ---------------------------------------------------------------------------
__global__ __launch_bounds__(256) void prep_k(
    const float* __restrict__ W_ih, const float* __restrict__ b_ih,
    const float* __restrict__ W_hh, const float* __restrict__ b_hh,
    const float* __restrict__ Wm, const float* __restrict__ W1,
    const float* __restrict__ W2, unsigned short* __restrict__ Wbig,
    unsigned short* __restrict__ Wmb, unsigned short* __restrict__ W1b,
    unsigned short* __restrict__ W2b, float* __restrict__ bias_big,
    float* __restrict__ stats, int* __restrict__ deg, int N) {
  int idx = blockIdx.x * 256 + threadIdx.x;
  if (idx < N) deg[idx] = 0;
  if (idx < 32768) {  // permuted Wbig: col c -> (gate g, feature f)
    int mp = idx >> 6;
    int k4 = (idx & 63) * 4;
    int w = mp >> 7, ci = (mp >> 4) & 7, l15 = mp & 15;
    int g = ci & 3, fi = ci >> 2;
    int f = w * 32 + fi * 16 + l15;
    const float* src = nullptr;
    int koff = 0;
    if (g <= 1) {
      int m = g * 128 + f;
      if (k4 < 128) { src = W_ih + (size_t)m * 128; koff = k4; }
      else          { src = W_hh + (size_t)m * 128; koff = k4 - 128; }
    } else if (g == 2) {
      if (k4 < 128) { src = W_ih + (size_t)(256 + f) * 128; koff = k4; }
    } else {
      if (k4 >= 128) { src = W_hh + (size_t)(256 + f) * 128; koff = k4 - 128; }
    }
    ushort4 o = make_ushort4(0, 0, 0, 0);
    if (src) o = f2b4(*(const float4*)(src + koff));
    *(ushort4*)&Wbig[(size_t)mp * 256 + k4] = o;
  }
  if (idx < 8192) {
    int m = idx >> 6;
    int k4 = (idx & 63) * 4;
    *(ushort4*)&Wmb[(size_t)m * 256 + k4] =
        f2b4(*(const float4*)(Wm + (size_t)m * 256 + k4));
    *(ushort4*)&W2b[(size_t)m * 256 + k4] =
        f2b4(*(const float4*)(W2 + (size_t)m * 256 + k4));
    int m2 = idx >> 5;
    int k42 = (idx & 31) * 4;
    *(ushort4*)&W1b[(size_t)m2 * 128 + k42] =
        f2b4(*(const float4*)(W1 + (size_t)m2 * 128 + k42));
  }
  if (blockIdx.x == 0) {
    int t = threadIdx.x;
    stats[t] = 0.f;
#pragma unroll
    for (int h = 0; h < 2; h++) {
      int mm = t + h * 256;
      float b;
      if (mm < 256) b = b_ih[mm] + b_hh[mm];
      else if (mm < 384) b = b_ih[mm];
      else b = b_hh[mm - 128];
      bias_big[mm] = b;
    }
  }
}

// ---------------------------------------------------------------------------
// cvt + hist in one dispatch (independent work, split by blockIdx)
// ---------------------------------------------------------------------------
__global__ __launch_bounds__(256) void cvthist_k(
    const int* __restrict__ edges, int* __restrict__ deg, int E,
    const float* __restrict__ x, unsigned short* __restrict__ xcat,
    int ngroups, int eblk) {
  if ((int)blockIdx.x < eblk) {
    int e = blockIdx.x * 256 + threadIdx.x;
    if (e < E) atomicAdd(&deg[edges[(size_t)E + e]], 1);
  } else {
    int g = (blockIdx.x - eblk) * 256 + threadIdx.x;
    if (g >= ngroups) return;
    int n = g >> 5;
    int j = (g & 31) * 4;
    float4 v = *(const float4*)&x[(size_t)n * 128 + j];
    *(ushort4*)&xcat[(size_t)n * 256 + j] = f2b4(v);
  }
}

// ---------------------------------------------------------------------------
// CSR scan + fill
// ---------------------------------------------------------------------------
__global__ __launch_bounds__(256) void scan1_k(const int* __restrict__ deg,
                                               int* __restrict__ off,
                                               int* __restrict__ bsums, int N) {
  __shared__ int s[256];
  int t = threadIdx.x;
  int i = blockIdx.x * 256 + t;
  int v = (i < N) ? deg[i] : 0;
  s[t] = v;
  __syncthreads();
#pragma unroll
  for (int d = 1; d < 256; d <<= 1) {
    int u = (t >= d) ? s[t - d] : 0;
    __syncthreads();
    s[t] += u;
    __syncthreads();
  }
  if (i < N) off[i] = s[t] - v;
  if (t == 255) bsums[blockIdx.x] = s[255];
}

__global__ __launch_bounds__(512) void scan2_k(int* __restrict__ bsums,
                                               int nb) {
  __shared__ int s[512];
  int t = threadIdx.x;
  int v = (t < nb) ? bsums[t] : 0;
  s[t] = v;
  __syncthreads();
#pragma unroll
  for (int d = 1; d < 512; d <<= 1) {
    int u = (t >= d) ? s[t - d] : 0;
    __syncthreads();
    s[t] += u;
    __syncthreads();
  }
  if (t < nb) bsums[t] = s[t] - v;
}

__global__ __launch_bounds__(256) void scan3_k(int* __restrict__ off,
                                               int* __restrict__ cur,
                                               const int* __restrict__ bsums,
                                               int N, int E) {
  int i = blockIdx.x * 256 + threadIdx.x;
  if (i < N) {
    int o = off[i] + bsums[blockIdx.x];
    off[i] = o;
    cur[i] = o;
  }
  if (i == 0) off[N] = E;
}

__global__ __launch_bounds__(256) void fill_k(const int* __restrict__ edges,
                                              int* __restrict__ cur,
                                              int* __restrict__ bucket, int E) {
  int e = blockIdx.x * 256 + threadIdx.x;
  if (e >= E) return;
  int src = edges[e];
  int dst = edges[(size_t)E + e];
  int pos = atomicAdd(&cur[dst], 1);
  bucket[pos] = src;
}

// ---------------------------------------------------------------------------
// gather-reduce: one wave/node, 2 edges/iteration (half-wave split), 4
// features/lane (ushort4 = 8B loads), depth-2 prefetch, shfl_xor combine.
// ---------------------------------------------------------------------------
__global__ __launch_bounds__(256) void gather_k(
    const int* __restrict__ off, const int* __restrict__ bucket,
    const unsigned short* __restrict__ xcat, unsigned short* __restrict__ aggm,
    unsigned short* __restrict__ Bcat, int N) {
  int node = blockIdx.x * 4 + (threadIdx.x >> 6);
  if (node >= N) return;
  const int lane = threadIdx.x & 63;
  const int half = lane >> 5;
  const int f = (lane & 31) * 4;
  const int j0 = off[node], jend = off[node + 1];
  float s0 = 0.f, s1 = 0.f, s2 = 0.f, s3 = 0.f;
  float m0 = -INFINITY, m1 = -INFINITY, m2 = -INFINITY, m3 = -INFINITY;
  int jj = j0 + half;
  int p0 = (jj < jend) ? bucket[jj] : 0;
  int p1 = (jj + 2 < jend) ? bucket[jj + 2] : 0;
  for (; jj < jend; jj += 2) {
    int src = p0;
    p0 = p1;
    p1 = (jj + 4 < jend) ? bucket[jj + 4] : 0;
    ushort4 a = *(const ushort4*)(xcat + (size_t)src * 256 + f);
    ushort4 b = *(const ushort4*)(xcat + (size_t)src * 256 + 128 + f);
    s0 += b2f(a.x);
    s1 += b2f(a.y);
    s2 += b2f(a.z);
    s3 += b2f(a.w);
    m0 = fmaxf(m0, b2f(b.x));
    m1 = fmaxf(m1, b2f(b.y));
    m2 = fmaxf(m2, b2f(b.z));
    m3 = fmaxf(m3, b2f(b.w));
  }
  // combine the two half-waves
  s0 += __shfl_xor(s0, 32);
  s1 += __shfl_xor(s1, 32);
  s2 += __shfl_xor(s2, 32);
  s3 += __shfl_xor(s3, 32);
  m0 = fmaxf(m0, __shfl_xor(m0, 32));
  m1 = fmaxf(m1, __shfl_xor(m1, 32));
  m2 = fmaxf(m2, __shfl_xor(m2, 32));
  m3 = fmaxf(m3, __shfl_xor(m3, 32));
  if (half == 0) {
    bool nz = jend > j0;
    ushort4 mv = nz ? make_ushort4(f2b(m0), f2b(m1), f2b(m2), f2b(m3))
                    : make_ushort4(0, 0, 0, 0);
    *(ushort4*)&aggm[(size_t)node * 128 + f] = mv;
    *(ushort4*)&Bcat[(size_t)node * 256 + f] =
        make_ushort4(f2b(s0), f2b(s1), f2b(s2), f2b(s3));
  }
}

// ---------------------------------------------------------------------------
// BatchNorm apply (scale/shift derived in-thread from stats; no bn_final)
// ---------------------------------------------------------------------------
__global__ __launch_bounds__(256) void bn_apply_k(
    float* __restrict__ out, const float* __restrict__ stats,
    const float* __restrict__ gamma, const float* __restrict__ beta,
    float invn, int nd4) {
  int g = blockIdx.x * 256 + threadIdx.x;
  if (g >= nd4) return;
  int d = (g & 31) * 4;
  float4 v = ((float4*)out)[g];
  float o[4] = {v.x, v.y, v.z, v.w};
#pragma unroll
  for (int i = 0; i < 4; i++) {
    float mean = stats[d + i] * invn;
    float var = fmaxf(stats[128 + d + i] * invn - mean * mean, 0.f);
    float sc = gamma[d + i] * rsqrtf(var + 1e-5f);
    o[i] = (o[i] - mean) * sc + beta[d + i];
  }
  ((float4*)out)[g] = make_float4(o[0], o[1], o[2], o[3]);
}

// ---------------------------------------------------------------------------
extern "C" void kernel_launch(void* const* d_in, const int* in_sizes, int n_in,
                              void* d_out, int out_size, void* d_ws,
                              size_t ws_size, hipStream_t stream) {
  (void)n_in;
  (void)out_size;
  (void)ws_size;
  const float* x = (const float*)d_in[0];
  const int* edges = (const int*)d_in[1];
  const float* W_aff = (const float*)d_in[2];
  const float* b_aff = (const float*)d_in[3];
  const float* W_ih = (const float*)d_in[4];
  const float* b_ih = (const float*)d_in[5];
  const float* W_hh = (const float*)d_in[6];
  const float* b_hh = (const float*)d_in[7];
  const float* W_merge = (const float*)d_in[8];
  const float* b_merge = (const float*)d_in[9];
  const float* epsp = (const float*)d_in[10];
  const float* W1 = (const float*)d_in[11];
  const float* b1 = (const float*)d_in[12];
  const float* W2 = (const float*)d_in[13];
  const float* b2 = (const float*)d_in[14];
  const float* gamma = (const float*)d_in[15];
  const float* beta = (const float*)d_in[16];

  const int N = in_sizes[0] / 128;
  const int E = in_sizes[1] / 2;
  const size_t nd = (size_t)N * 128;

  // ---- workspace (~136 MB) ----
  char* base = (char*)d_ws;
  unsigned short* xcat = (unsigned short*)base;               // [xb|xib] Nx256
  unsigned short* Bcat = (unsigned short*)(base + (size_t)N * 512);  // [aggs|rnn]
  unsigned short* aggm = (unsigned short*)(base + (size_t)N * 1024); // Nx128
  unsigned short* Wbig = (unsigned short*)(base + (size_t)N * 1280);
  unsigned short* Wmb = Wbig + 512 * 256;
  unsigned short* W1b = Wmb + 128 * 256;
  unsigned short* W2b = W1b + 256 * 128;
  float* bias_big = (float*)(W2b + 128 * 256);
  float* stats = bias_big + 512;
  int* deg = (int*)(stats + 512);
  int* off = deg + N;
  int* cur = off + N + 1;
  int* bucket = cur + N;
  int* bsums = bucket + E;
  float* out = (float*)d_out;

  const int ny = (N + 127) / 128;
  const int nblk = (N + 255) / 256;
  const int eblk = (E + 255) / 256;
  const int cvtblk = (int)((nd / 4 + 255) / 256);
  const int pgrid = nblk > 128 ? nblk : 128;
  dim3 blk(256);

  prep_k<<<pgrid, blk, 0, stream>>>(W_ih, b_ih, W_hh, b_hh, W_merge, W1, W2,
                                    Wbig, Wmb, W1b, W2b, bias_big, stats, deg,
                                    N);
  cvthist_k<<<eblk + cvtblk, blk, 0, stream>>>(edges, deg, E, x, xcat,
                                               (int)(nd / 4), eblk);
  scan1_k<<<nblk, blk, 0, stream>>>(deg, off, bsums, N);
  scan2_k<<<1, 512, 0, stream>>>(bsums, nblk);
  scan3_k<<<nblk, blk, 0, stream>>>(off, cur, bsums, N, E);
  fill_k<<<eblk, blk, 0, stream>>>(edges, cur, bucket, E);

  // xib = bf16(xb @ W_aff^T + b_aff) into xcat right half
  mgemm_k<<<dim3(1, ny), blk, 0, stream>>>(xcat, 256, W_aff, b_aff, xcat + 128,
                                           256, N, 128, 128);
  gather_k<<<(N + 3) / 4, blk, 0, stream>>>(off, bucket, xcat, aggm, Bcat, N);
  grurnn_k<<<(N + 31) / 32, blk, 0, stream>>>(aggm, xcat, Wbig, bias_big,
                                              Bcat, N);
  backbone_k<<<(N + 63) / 64, blk, 0, stream>>>(Bcat, xcat, Wmb, b_merge, W1b,
                                                b1, W2b, b2, epsp, out, stats,
                                                N);
  bn_apply_k<<<(int)((nd / 4 + 255) / 256), blk, 0, stream>>>(
      out, stats, gamma, beta, 1.f / (float)N, (int)(nd / 4));
}